// Round 1
// baseline (245.463 us; speedup 1.0000x reference)
//
#include <hip/hip_runtime.h>
#include <math.h>

#define B_ 8
#define NL 64
#define NR 512
#define FD 128
#define HID 128
#define KM 10
#define P_ 262144
#define M_ 131072
#define LDH 136   // padded LDS row stride in bf16 elems (272B = 16B-aligned, breaks bank conflicts)

typedef short bf16x8 __attribute__((ext_vector_type(8)));
typedef float f32x4 __attribute__((ext_vector_type(4)));

static __device__ __forceinline__ ushort f2bf(float x) {
    union { float f; unsigned int u; } v; v.f = x;
    unsigned int r = v.u + 0x7FFFu + ((v.u >> 16) & 1u);
    return (ushort)(r >> 16);
}
static __device__ __forceinline__ float bf2f(ushort s) {
    union { unsigned int u; float f; } v; v.u = ((unsigned int)s) << 16;
    return v.f;
}
static __device__ __forceinline__ float elu1(float x) {
    return x > 0.f ? x : (expf(x) - 1.f);
}

// ---------------- k1: U = flig @ W1_top + b1 ; V = frec @ W1_bot ----------------
__global__ __launch_bounds__(128) void k1_uv(const float* __restrict__ flig,
        const float* __restrict__ frec, const float* __restrict__ W1,
        const float* __restrict__ b1, float* __restrict__ U, float* __restrict__ V) {
    __shared__ float fr[8][128];
    int bid = blockIdx.x, c = threadIdx.x;
    const float* feat; const float* Wb; float* outp; float bias;
    if (bid < 64) {
        int rowbase = bid * 8;
        feat = flig + rowbase * FD; Wb = W1; outp = U + rowbase * HID; bias = b1[c];
    } else {
        int rowbase = (bid - 64) * 8;
        feat = frec + rowbase * FD; Wb = W1 + FD * HID; outp = V + rowbase * HID; bias = 0.f;
    }
    #pragma unroll
    for (int rr = 0; rr < 8; rr++) fr[rr][c] = feat[rr * FD + c];
    __syncthreads();
    float acc[8];
    #pragma unroll
    for (int rr = 0; rr < 8; rr++) acc[rr] = bias;
    #pragma unroll 4
    for (int k = 0; k < FD; k++) {
        float wv = Wb[k * HID + c];
        #pragma unroll
        for (int rr = 0; rr < 8; rr++) acc[rr] += fr[rr][k] * wv;
    }
    #pragma unroll
    for (int rr = 0; rr < 8; rr++) outp[rr * HID + c] = acc[rr];
}

// ---------------- k1b: per-batch column sums of U,U^2,V,V^2 ----------------
__global__ __launch_bounds__(256) void k1b_stats(const float* __restrict__ U, const float* __restrict__ V,
        float* __restrict__ SU, float* __restrict__ SU2, float* __restrict__ SV, float* __restrict__ SV2) {
    int b = blockIdx.x;
    int t = threadIdx.x, c = t & 127, half = t >> 7;
    float su = 0, su2 = 0, sv = 0, sv2 = 0;
    for (int l = half; l < NL; l += 2) { float u = U[(b * NL + l) * HID + c]; su += u; su2 += u * u; }
    for (int r = half; r < NR; r += 2) { float v = V[(b * NR + r) * HID + c]; sv += v; sv2 += v * v; }
    __shared__ float red[4][2][128];
    red[0][half][c] = su; red[1][half][c] = su2; red[2][half][c] = sv; red[3][half][c] = sv2;
    __syncthreads();
    if (t < 128) {
        SU[b * 128 + t]  = red[0][0][t] + red[0][1][t];
        SU2[b * 128 + t] = red[1][0][t] + red[1][1][t];
        SV[b * 128 + t]  = red[2][0][t] + red[2][1][t];
        SV2[b * 128 + t] = red[3][0][t] + red[3][1][t];
    }
}

// ---------------- k2: finalize BN1 (mean/var via exact U+V decomposition) ----------------
__global__ __launch_bounds__(128) void k2_bn1(const float* __restrict__ SU, const float* __restrict__ SU2,
        const float* __restrict__ SV, const float* __restrict__ SV2,
        const float* __restrict__ g1, const float* __restrict__ beta1,
        float* __restrict__ scale1, float* __restrict__ shift1) {
    int c = threadIdx.x;
    float sum = 0.f, ssq = 0.f;
    for (int b = 0; b < B_; b++) {
        float su = SU[b * 128 + c], sv = SV[b * 128 + c];
        sum += (float)NR * su + (float)NL * sv;
        ssq += (float)NR * SU2[b * 128 + c] + 2.f * su * sv + (float)NL * SV2[b * 128 + c];
    }
    float inv = 1.f / (float)P_;
    float mean = sum * inv;
    float var = ssq * inv - mean * mean;
    float sc = g1[c] * rsqrtf(var + 1e-5f);
    scale1[c] = sc; shift1[c] = beta1[c] - mean * sc;
}

// ---------------- k3: a2 = h @ Wc1 + bc1 (bf16 MFMA), h computed on the fly ----------------
__global__ __launch_bounds__(256) void k3_gemm(const float* __restrict__ U, const float* __restrict__ V,
        const float* __restrict__ Wc1, const float* __restrict__ bc1,
        const float* __restrict__ scale1, const float* __restrict__ shift1,
        ushort* __restrict__ a2, float* __restrict__ bn2s, float* __restrict__ bn2s2) {
    __shared__ ushort hT[128 * LDH];
    __shared__ ushort wT[128 * LDH];
    __shared__ float sred[4][128];
    __shared__ float s2red[4][128];
    int bid = blockIdx.x, t = threadIdx.x;
    int i0 = bid * 128;
    int bl = i0 >> 9;                          // shared lig row for whole tile
    int vbase = ((bl >> 6) << 9) + (i0 & 511); // first rec row
    // stage Wc1^T (B operand: WT[n][k])
    for (int idx = t; idx < HID * HID; idx += 256) {
        int k = idx >> 7, n = idx & 127;
        wT[n * LDH + k] = f2bf(Wc1[k * HID + n]);
    }
    // stage h tile (A operand: h[row][k]) — h = elu((U+V)*scale1 + shift1)
    {
        int c = t & 127, half = t >> 7;
        float uc = U[bl * HID + c];
        float sc = scale1[c], sh = shift1[c];
        for (int rr = half; rr < 128; rr += 2) {
            float v = V[(vbase + rr) * HID + c];
            hT[rr * LDH + c] = f2bf(elu1((uc + v) * sc + sh));
        }
    }
    __syncthreads();
    int w = t >> 6, lane = t & 63;
    int wrow = w * 32, lrow = lane & 15, kgrp = lane >> 4;
    f32x4 acc[2][8];
    #pragma unroll
    for (int mi = 0; mi < 2; mi++)
        #pragma unroll
        for (int ni = 0; ni < 8; ni++) acc[mi][ni] = (f32x4){0.f, 0.f, 0.f, 0.f};
    #pragma unroll
    for (int ks = 0; ks < 4; ks++) {
        int ko = ks * 32 + kgrp * 8;
        bf16x8 a0 = *(const bf16x8*)&hT[(wrow + lrow) * LDH + ko];
        bf16x8 a1 = *(const bf16x8*)&hT[(wrow + 16 + lrow) * LDH + ko];
        #pragma unroll
        for (int ni = 0; ni < 8; ni++) {
            bf16x8 bfr = *(const bf16x8*)&wT[(ni * 16 + lrow) * LDH + ko];
            acc[0][ni] = __builtin_amdgcn_mfma_f32_16x16x32_bf16(a0, bfr, acc[0][ni], 0, 0, 0);
            acc[1][ni] = __builtin_amdgcn_mfma_f32_16x16x32_bf16(a1, bfr, acc[1][ni], 0, 0, 0);
        }
    }
    // bias + per-column stats + stage a2 back into hT (same stride => each wave owns its rows)
    float s[8], s2[8];
    #pragma unroll
    for (int ni = 0; ni < 8; ni++) {
        float bcv = bc1[ni * 16 + lrow];
        s[ni] = 0.f; s2[ni] = 0.f;
        #pragma unroll
        for (int mi = 0; mi < 2; mi++) {
            #pragma unroll
            for (int reg = 0; reg < 4; reg++) {
                float vv = acc[mi][ni][reg] + bcv;
                s[ni] += vv; s2[ni] += vv * vv;
                int row = wrow + mi * 16 + kgrp * 4 + reg;
                hT[row * LDH + ni * 16 + lrow] = f2bf(vv);
            }
        }
    }
    #pragma unroll
    for (int ni = 0; ni < 8; ni++) {
        s[ni] += __shfl_xor(s[ni], 16);  s[ni] += __shfl_xor(s[ni], 32);
        s2[ni] += __shfl_xor(s2[ni], 16); s2[ni] += __shfl_xor(s2[ni], 32);
    }
    if (lane < 16) {
        #pragma unroll
        for (int ni = 0; ni < 8; ni++) { sred[w][ni * 16 + lane] = s[ni]; s2red[w][ni * 16 + lane] = s2[ni]; }
    }
    __syncthreads();
    // coalesced copy-out of a2 tile
    for (int idx = t; idx < 2048; idx += 256) {
        int rr = idx >> 4, cc = (idx & 15) * 8;
        bf16x8 vv = *(const bf16x8*)&hT[rr * LDH + cc];
        *(bf16x8*)&a2[i0 * HID + rr * HID + cc] = vv;
    }
    if (t < 128) {
        bn2s[bid * 128 + t]  = sred[0][t] + sred[1][t] + sred[2][t] + sred[3][t];
        bn2s2[bid * 128 + t] = s2red[0][t] + s2red[1][t] + s2red[2][t] + s2red[3][t];
    }
}

// ---------------- k4a/k4b: reduce BN2 partials -> scale2/shift2 ----------------
__global__ __launch_bounds__(256) void k4a(const float* __restrict__ bn2s, const float* __restrict__ bn2s2,
        float* __restrict__ l2s, float* __restrict__ l2s2) {
    int j = blockIdx.x, t = threadIdx.x, c = t & 127, half = t >> 7;
    float s = 0, s2 = 0;
    for (int rr = half; rr < 32; rr += 2) {
        int row = j * 32 + rr;
        s += bn2s[row * 128 + c]; s2 += bn2s2[row * 128 + c];
    }
    __shared__ float red[2][2][128];
    red[0][half][c] = s; red[1][half][c] = s2;
    __syncthreads();
    if (t < 128) { l2s[j * 128 + t] = red[0][0][t] + red[0][1][t]; l2s2[j * 128 + t] = red[1][0][t] + red[1][1][t]; }
}

__global__ __launch_bounds__(128) void k4b(const float* __restrict__ l2s, const float* __restrict__ l2s2,
        const float* __restrict__ gc, const float* __restrict__ betac,
        float* __restrict__ scale2, float* __restrict__ shift2) {
    int c = threadIdx.x;
    float s = 0, s2 = 0;
    for (int j = 0; j < 64; j++) { s += l2s[j * 128 + c]; s2 += l2s2[j * 128 + c]; }
    float inv = 1.f / (float)P_;
    float mean = s * inv, var = s2 * inv - mean * mean;
    float sc = gc[c] * rsqrtf(var + 1e-5f);
    scale2[c] = sc; shift2[c] = betac[c] - mean * sc;
}

// ---------------- k5: contact epilogue + contact_truth ----------------
__global__ __launch_bounds__(256) void k5_contact(const ushort* __restrict__ a2,
        const float* __restrict__ scale2, const float* __restrict__ shift2,
        const float* __restrict__ Wc2, const float* __restrict__ bc2,
        const float* __restrict__ posl, const float* __restrict__ posr,
        float* __restrict__ outc, float* __restrict__ outt) {
    int t = threadIdx.x;
    int row = blockIdx.x * 16 + (t >> 4);
    int cg = (t & 15) * 8;
    bf16x8 v = *(const bf16x8*)&a2[row * HID + cg];
    float s = 0.f;
    #pragma unroll
    for (int e = 0; e < 8; e++) {
        int c = cg + e;
        float x = bf2f((ushort)v[e]) * scale2[c] + shift2[c];
        s += fmaxf(x, 0.f) * Wc2[c];
    }
    s += __shfl_xor(s, 1); s += __shfl_xor(s, 2); s += __shfl_xor(s, 4); s += __shfl_xor(s, 8);
    if ((t & 15) == 0) {
        outc[row] = s + bc2[0];
        int bl = row >> 9, b = row >> 15, r = row & 511;
        float dx = posl[bl * 3]     - posr[(b * NR + r) * 3];
        float dy = posl[bl * 3 + 1] - posr[(b * NR + r) * 3 + 1];
        float dz = posl[bl * 3 + 2] - posr[(b * NR + r) * 3 + 2];
        float y = sqrtf(dx * dx + dy * dy + dz * dz);
        outt[row] = (y < 8.0f) ? 1.0f : 0.0f;
    }
}

// ---------------- k6: MDN (gather h via U+V recompute, 128x32 MFMA, full epilogue) ----------------
__global__ __launch_bounds__(256) void k6_mdn(const int* __restrict__ mask,
        const float* __restrict__ U, const float* __restrict__ V,
        const float* __restrict__ scale1, const float* __restrict__ shift1,
        const float* __restrict__ Wpi, const float* __restrict__ Wsig, const float* __restrict__ Wmu,
        const float* __restrict__ bpi, const float* __restrict__ bsig, const float* __restrict__ bmu,
        const float* __restrict__ posl, const float* __restrict__ posr,
        float* __restrict__ out_logpi, float* __restrict__ out_sigma, float* __restrict__ out_mu,
        float* __restrict__ mdn_psum, float* __restrict__ mdn_pcnt) {
    __shared__ ushort hT[128 * LDH];
    __shared__ ushort wT[32 * LDH];
    __shared__ float zl[128 * 33];
    __shared__ int midx[128];
    __shared__ float mdnv[128];
    __shared__ int mdnb[128];
    int bid = blockIdx.x, t = threadIdx.x;
    int m0 = bid * 128;
    if (t < 128) midx[t] = mask[m0 + t];
    // stage packed weights [32 cols][128 k] = [Wpi | Wsig | Wmu | 0 0]^T
    for (int idx = t; idx < 32 * 128; idx += 256) {
        int j = idx >> 7, k = idx & 127;
        float wv = 0.f;
        if (j < 10) wv = Wpi[k * KM + j];
        else if (j < 20) wv = Wsig[k * KM + (j - 10)];
        else if (j < 30) wv = Wmu[k * KM + (j - 20)];
        wT[j * LDH + k] = f2bf(wv);
    }
    __syncthreads();
    {
        int c = t & 127, half = t >> 7;
        float sc = scale1[c], sh = shift1[c];
        for (int rr = half; rr < 128; rr += 2) {
            int i = midx[rr];
            int bl = i >> 9, b = i >> 15, r = i & 511;
            float x = (U[bl * HID + c] + V[(b * NR + r) * HID + c]) * sc + sh;
            hT[rr * LDH + c] = f2bf(elu1(x));
        }
    }
    __syncthreads();
    int w = t >> 6, lane = t & 63;
    int wrow = w * 32, lrow = lane & 15, kgrp = lane >> 4;
    f32x4 acc[2][2];
    #pragma unroll
    for (int mi = 0; mi < 2; mi++)
        #pragma unroll
        for (int ni = 0; ni < 2; ni++) acc[mi][ni] = (f32x4){0.f, 0.f, 0.f, 0.f};
    #pragma unroll
    for (int ks = 0; ks < 4; ks++) {
        int ko = ks * 32 + kgrp * 8;
        bf16x8 a0 = *(const bf16x8*)&hT[(wrow + lrow) * LDH + ko];
        bf16x8 a1 = *(const bf16x8*)&hT[(wrow + 16 + lrow) * LDH + ko];
        bf16x8 b0 = *(const bf16x8*)&wT[lrow * LDH + ko];
        bf16x8 b1 = *(const bf16x8*)&wT[(16 + lrow) * LDH + ko];
        acc[0][0] = __builtin_amdgcn_mfma_f32_16x16x32_bf16(a0, b0, acc[0][0], 0, 0, 0);
        acc[0][1] = __builtin_amdgcn_mfma_f32_16x16x32_bf16(a0, b1, acc[0][1], 0, 0, 0);
        acc[1][0] = __builtin_amdgcn_mfma_f32_16x16x32_bf16(a1, b0, acc[1][0], 0, 0, 0);
        acc[1][1] = __builtin_amdgcn_mfma_f32_16x16x32_bf16(a1, b1, acc[1][1], 0, 0, 0);
    }
    #pragma unroll
    for (int mi = 0; mi < 2; mi++)
        #pragma unroll
        for (int ni = 0; ni < 2; ni++)
            #pragma unroll
            for (int reg = 0; reg < 4; reg++) {
                int row = wrow + mi * 16 + kgrp * 4 + reg;
                zl[row * 33 + ni * 16 + lrow] = acc[mi][ni][reg];
            }
    __syncthreads();
    if (t < 128) {
        float z[30];
        #pragma unroll
        for (int j = 0; j < 30; j++) z[j] = zl[t * 33 + j];
        float lp[10], mx = -1e30f;
        #pragma unroll
        for (int j = 0; j < 10; j++) { lp[j] = z[j] + bpi[j]; mx = fmaxf(mx, lp[j]); }
        float se = 0.f;
        #pragma unroll
        for (int j = 0; j < 10; j++) se += expf(lp[j] - mx);
        float lse = mx + logf(se);
        #pragma unroll
        for (int j = 0; j < 10; j++) lp[j] -= lse;
        float sg[10], muv[10];
        #pragma unroll
        for (int j = 0; j < 10; j++) sg[j] = elu1(z[10 + j] + bsig[j]) + 1.1f;
        #pragma unroll
        for (int j = 0; j < 10; j++) muv[j] = elu1(z[20 + j] + bmu[j]) + 1.0f;
        int i = midx[t];
        int bl = i >> 9, b = i >> 15, r = i & 511;
        float dx = posl[bl * 3]     - posr[(b * NR + r) * 3];
        float dy = posl[bl * 3 + 1] - posr[(b * NR + r) * 3 + 1];
        float dz = posl[bl * 3 + 2] - posr[(b * NR + r) * 3 + 2];
        float y = sqrtf(dx * dx + dy * dy + dz * dz);
        float tt[10], mm = -1e30f;
        #pragma unroll
        for (int j = 0; j < 10; j++) {
            float q = (y - muv[j]) / sg[j];
            float llv = -0.5f * q * q - logf(sg[j]) - 0.91893853320467274f;
            tt[j] = lp[j] + llv; mm = fmaxf(mm, tt[j]);
        }
        float s2e = 0.f;
        #pragma unroll
        for (int j = 0; j < 10; j++) s2e += expf(tt[j] - mm);
        float mdn = -(mm + logf(s2e));
        int mrow = m0 + t;
        #pragma unroll
        for (int j = 0; j < 10; j++) out_logpi[mrow * 10 + j] = lp[j];
        #pragma unroll
        for (int j = 0; j < 10; j++) out_sigma[mrow * 10 + j] = sg[j];
        #pragma unroll
        for (int j = 0; j < 10; j++) out_mu[mrow * 10 + j] = muv[j];
        mdnv[t] = mdn; mdnb[t] = b;
    }
    __syncthreads();
    if (t < 8) {  // deterministic fixed-order per-batch partial sums
        float s = 0.f; int cnt = 0;
        for (int rr = 0; rr < 128; rr++) if (mdnb[rr] == t) { s += mdnv[rr]; cnt++; }
        mdn_psum[bid * 8 + t] = s; mdn_pcnt[bid * 8 + t] = (float)cnt;
    }
}

// ---------------- k7: prob = segment mean ----------------
__global__ __launch_bounds__(256) void k7_prob(const float* __restrict__ psum, const float* __restrict__ pcnt,
        float* __restrict__ prob) {
    int b = blockIdx.x, t = threadIdx.x;
    float s = 0, c = 0;
    for (int idx = t; idx < 1024; idx += 256) { s += psum[idx * 8 + b]; c += pcnt[idx * 8 + b]; }
    __shared__ float rs[256], rc[256];
    rs[t] = s; rc[t] = c;
    __syncthreads();
    for (int off = 128; off > 0; off >>= 1) {
        if (t < off) { rs[t] += rs[t + off]; rc[t] += rc[t + off]; }
        __syncthreads();
    }
    if (t == 0) prob[b] = rs[0] / fmaxf(rc[0], 1.f);
}

extern "C" void kernel_launch(void* const* d_in, const int* in_sizes, int n_in,
                              void* d_out, int out_size, void* d_ws, size_t ws_size,
                              hipStream_t stream) {
    const float* flig  = (const float*)d_in[0];
    const float* posl  = (const float*)d_in[1];
    const float* frec  = (const float*)d_in[3];
    const float* posr  = (const float*)d_in[4];
    const int*   mask  = (const int*)d_in[6];
    const float* W1    = (const float*)d_in[7];
    const float* b1    = (const float*)d_in[8];
    const float* g1    = (const float*)d_in[9];
    const float* beta1 = (const float*)d_in[10];
    const float* Wpi   = (const float*)d_in[11];
    const float* bpi   = (const float*)d_in[12];
    const float* Wsig  = (const float*)d_in[13];
    const float* bsig  = (const float*)d_in[14];
    const float* Wmu   = (const float*)d_in[15];
    const float* bmu   = (const float*)d_in[16];
    const float* Wc1   = (const float*)d_in[17];
    const float* bc1   = (const float*)d_in[18];
    const float* gc    = (const float*)d_in[19];
    const float* betac = (const float*)d_in[20];
    const float* Wc2   = (const float*)d_in[21];
    const float* bc2   = (const float*)d_in[22];

    float* ws = (float*)d_ws;
    float* U      = ws;                // 65536
    float* V      = ws + 65536;        // 524288
    float* SU     = ws + 589824;       // 1024
    float* SU2    = ws + 590848;
    float* SV     = ws + 591872;
    float* SV2    = ws + 592896;
    float* scale1 = ws + 593920;       // 128
    float* shift1 = ws + 594048;
    float* scale2 = ws + 594176;
    float* shift2 = ws + 594304;
    float* bn2s   = ws + 594432;       // 2048*128
    float* bn2s2  = ws + 856576;       // 2048*128
    float* l2s    = ws + 1118720;      // 64*128
    float* l2s2   = ws + 1126912;
    float* psum   = ws + 1135104;      // 1024*8
    float* pcnt   = ws + 1143296;
    ushort* a2    = (ushort*)(ws + 1151488);  // P*128 bf16 = 67.1 MB

    float* out = (float*)d_out;
    float* out_logpi   = out;
    float* out_sigma   = out + 1310720;
    float* out_mu      = out + 2621440;
    float* out_prob    = out + 3932160;
    float* out_contact = out + 3932168;
    float* out_truth   = out + 4194312;

    k1_uv<<<dim3(576), dim3(128), 0, stream>>>(flig, frec, W1, b1, U, V);
    k1b_stats<<<dim3(8), dim3(256), 0, stream>>>(U, V, SU, SU2, SV, SV2);
    k2_bn1<<<dim3(1), dim3(128), 0, stream>>>(SU, SU2, SV, SV2, g1, beta1, scale1, shift1);
    k3_gemm<<<dim3(2048), dim3(256), 0, stream>>>(U, V, Wc1, bc1, scale1, shift1, a2, bn2s, bn2s2);
    k4a<<<dim3(64), dim3(256), 0, stream>>>(bn2s, bn2s2, l2s, l2s2);
    k4b<<<dim3(1), dim3(128), 0, stream>>>(l2s, l2s2, gc, betac, scale2, shift2);
    k5_contact<<<dim3(16384), dim3(256), 0, stream>>>(a2, scale2, shift2, Wc2, bc2, posl, posr, out_contact, out_truth);
    k6_mdn<<<dim3(1024), dim3(256), 0, stream>>>(mask, U, V, scale1, shift1, Wpi, Wsig, Wmu,
        bpi, bsig, bmu, posl, posr, out_logpi, out_sigma, out_mu, psum, pcnt);
    k7_prob<<<dim3(8), dim3(256), 0, stream>>>(psum, pcnt, out_prob);
}

// Round 2
// 189.712 us; speedup vs baseline: 1.2939x; 1.2939x over previous
//
#include <hip/hip_runtime.h>
#include <math.h>

#define B_ 8
#define NL 64
#define NR 512
#define FD 128
#define HID 128
#define KM 10
#define P_ 262144
#define M_ 131072
#define LDH 136   // padded LDS row stride in bf16 elems (272B, breaks bank conflicts)

typedef short bf16x8 __attribute__((ext_vector_type(8)));
typedef float f32x4 __attribute__((ext_vector_type(4)));
typedef ushort u16x4 __attribute__((ext_vector_type(4)));

static __device__ __forceinline__ ushort f2bf(float x) {
    union { float f; unsigned int u; } v; v.f = x;
    unsigned int r = v.u + 0x7FFFu + ((v.u >> 16) & 1u);
    return (ushort)(r >> 16);
}
static __device__ __forceinline__ float elu1(float x) {
    return x > 0.f ? x : (expf(x) - 1.f);
}

// ---------------- k0: precompute bf16 weights (Wc1^T, packed MDN heads) ----------------
__global__ __launch_bounds__(256) void k0_prep(const float* __restrict__ Wc1,
        const float* __restrict__ Wpi, const float* __restrict__ Wsig, const float* __restrict__ Wmu,
        ushort* __restrict__ wc1T, ushort* __restrict__ whg) {
    int t = threadIdx.x;
    for (int idx = t; idx < HID * HID; idx += 256) {
        int k = idx >> 7, n = idx & 127;
        wc1T[n * 128 + k] = f2bf(Wc1[idx]);   // Wc1[k][n] -> wc1T[n][k]
    }
    for (int idx = t; idx < 32 * 128; idx += 256) {
        int j = idx >> 7, k = idx & 127;
        float wv = 0.f;
        if (j < 10) wv = Wpi[k * KM + j];
        else if (j < 20) wv = Wsig[k * KM + (j - 10)];
        else if (j < 30) wv = Wmu[k * KM + (j - 20)];
        whg[j * 128 + k] = f2bf(wv);
    }
}

// ---------------- k1: U = flig @ W1_top + b1 ; V = frec @ W1_bot ; emit col partials ----------------
__global__ __launch_bounds__(128) void k1_uv(const float* __restrict__ flig,
        const float* __restrict__ frec, const float* __restrict__ W1,
        const float* __restrict__ b1, float* __restrict__ U, float* __restrict__ V,
        float* __restrict__ partS, float* __restrict__ partS2) {
    __shared__ float fr[8][128];
    int bid = blockIdx.x, c = threadIdx.x;
    const float* feat; const float* Wb; float* outp; float bias;
    if (bid < 64) {
        int rowbase = bid * 8;
        feat = flig + rowbase * FD; Wb = W1; outp = U + rowbase * HID; bias = b1[c];
    } else {
        int rowbase = (bid - 64) * 8;
        feat = frec + rowbase * FD; Wb = W1 + FD * HID; outp = V + rowbase * HID; bias = 0.f;
    }
    #pragma unroll
    for (int rr = 0; rr < 8; rr++) fr[rr][c] = feat[rr * FD + c];
    __syncthreads();
    float acc[8];
    #pragma unroll
    for (int rr = 0; rr < 8; rr++) acc[rr] = bias;
    #pragma unroll 4
    for (int k = 0; k < FD; k++) {
        float wv = Wb[k * HID + c];
        #pragma unroll
        for (int rr = 0; rr < 8; rr++) acc[rr] += fr[rr][k] * wv;
    }
    float su = 0.f, su2 = 0.f;
    #pragma unroll
    for (int rr = 0; rr < 8; rr++) {
        outp[rr * HID + c] = acc[rr];
        su += acc[rr]; su2 += acc[rr] * acc[rr];
    }
    partS[bid * 128 + c] = su;
    partS2[bid * 128 + c] = su2;
}

// ---------------- k2a: per-batch reduce of partials ----------------
__global__ __launch_bounds__(256) void k2a(const float* __restrict__ partS, const float* __restrict__ partS2,
        float* __restrict__ SU, float* __restrict__ SU2, float* __restrict__ SV, float* __restrict__ SV2) {
    int b = blockIdx.x, t = threadIdx.x, c = t & 127, half = t >> 7;
    if (half == 0) {
        float s = 0.f, s2 = 0.f;
        #pragma unroll
        for (int j = 0; j < 8; j++) { int row = b * 8 + j; s += partS[row * 128 + c]; s2 += partS2[row * 128 + c]; }
        SU[b * 128 + c] = s; SU2[b * 128 + c] = s2;
    } else {
        float s = 0.f, s2 = 0.f;
        for (int j = 0; j < 64; j++) { int row = 64 + b * 64 + j; s += partS[row * 128 + c]; s2 += partS2[row * 128 + c]; }
        SV[b * 128 + c] = s; SV2[b * 128 + c] = s2;
    }
}

// ---------------- k2b: finalize BN1 scale/shift ----------------
__global__ __launch_bounds__(128) void k2b(const float* __restrict__ SU, const float* __restrict__ SU2,
        const float* __restrict__ SV, const float* __restrict__ SV2,
        const float* __restrict__ g1, const float* __restrict__ beta1,
        float* __restrict__ scale1, float* __restrict__ shift1) {
    int c = threadIdx.x;
    float sum = 0.f, ssq = 0.f;
    #pragma unroll
    for (int b = 0; b < B_; b++) {
        float su = SU[b * 128 + c], sv = SV[b * 128 + c];
        sum += (float)NR * su + (float)NL * sv;
        ssq += (float)NR * SU2[b * 128 + c] + 2.f * su * sv + (float)NL * SV2[b * 128 + c];
    }
    float inv = 1.f / (float)P_;
    float mean = sum * inv;
    float var = ssq * inv - mean * mean;
    float sc = g1[c] * rsqrtf(var + 1e-5f);
    scale1[c] = sc; shift1[c] = beta1[c] - mean * sc;
}

// ---------------- k3: BN2 stats pass — z = h @ Wc1 + bc1, accumulate col sum/sumsq, NO store ----------------
__global__ __launch_bounds__(256) void k3_stats(const float* __restrict__ U, const float* __restrict__ V,
        const ushort* __restrict__ wc1T, const float* __restrict__ bc1,
        const float* __restrict__ scale1, const float* __restrict__ shift1,
        float* __restrict__ bn2s, float* __restrict__ bn2s2) {
    __shared__ ushort hT[128 * LDH];
    __shared__ ushort wT[128 * LDH];
    __shared__ float sred[4][128];
    __shared__ float s2red[4][128];
    int bid = blockIdx.x, t = threadIdx.x;
    int i0 = bid * 128;
    int bl = i0 >> 9;
    int vbase = ((bl >> 6) << 9) + (i0 & 511);
    // stage Wc1^T from pre-converted bf16 (vectorized, conflict-free b128 writes)
    #pragma unroll
    for (int it = 0; it < 8; it++) {
        int chunk = t + it * 256;
        int n = chunk >> 4, ko = (chunk & 15) * 8;
        *(bf16x8*)&wT[n * LDH + ko] = *(const bf16x8*)&wc1T[n * 128 + ko];
    }
    // stage h tile: h = elu((U+V)*scale1 + shift1), float4 loads
    {
        int c4 = (t & 31) * 4, rg = t >> 5;
        float4 uu = *(const float4*)&U[bl * HID + c4];
        float4 sc = *(const float4*)&scale1[c4];
        float4 sh = *(const float4*)&shift1[c4];
        for (int rr = rg; rr < 128; rr += 8) {
            float4 v = *(const float4*)&V[(vbase + rr) * HID + c4];
            u16x4 o;
            o.x = f2bf(elu1((uu.x + v.x) * sc.x + sh.x));
            o.y = f2bf(elu1((uu.y + v.y) * sc.y + sh.y));
            o.z = f2bf(elu1((uu.z + v.z) * sc.z + sh.z));
            o.w = f2bf(elu1((uu.w + v.w) * sc.w + sh.w));
            *(u16x4*)&hT[rr * LDH + c4] = o;
        }
    }
    __syncthreads();
    int w = t >> 6, lane = t & 63;
    int wrow = w * 32, lrow = lane & 15, kgrp = lane >> 4;
    f32x4 acc[2][8];
    #pragma unroll
    for (int mi = 0; mi < 2; mi++)
        #pragma unroll
        for (int ni = 0; ni < 8; ni++) acc[mi][ni] = (f32x4){0.f, 0.f, 0.f, 0.f};
    #pragma unroll
    for (int ks = 0; ks < 4; ks++) {
        int ko = ks * 32 + kgrp * 8;
        bf16x8 a0 = *(const bf16x8*)&hT[(wrow + lrow) * LDH + ko];
        bf16x8 a1 = *(const bf16x8*)&hT[(wrow + 16 + lrow) * LDH + ko];
        #pragma unroll
        for (int ni = 0; ni < 8; ni++) {
            bf16x8 bfr = *(const bf16x8*)&wT[(ni * 16 + lrow) * LDH + ko];
            acc[0][ni] = __builtin_amdgcn_mfma_f32_16x16x32_bf16(a0, bfr, acc[0][ni], 0, 0, 0);
            acc[1][ni] = __builtin_amdgcn_mfma_f32_16x16x32_bf16(a1, bfr, acc[1][ni], 0, 0, 0);
        }
    }
    // per-column stats (with bc1 bias), no z store
    float s[8], s2[8];
    #pragma unroll
    for (int ni = 0; ni < 8; ni++) {
        float bcv = bc1[ni * 16 + lrow];
        s[ni] = 0.f; s2[ni] = 0.f;
        #pragma unroll
        for (int mi = 0; mi < 2; mi++)
            #pragma unroll
            for (int reg = 0; reg < 4; reg++) {
                float vv = acc[mi][ni][reg] + bcv;
                s[ni] += vv; s2[ni] += vv * vv;
            }
    }
    #pragma unroll
    for (int ni = 0; ni < 8; ni++) {
        s[ni] += __shfl_xor(s[ni], 16);  s[ni] += __shfl_xor(s[ni], 32);
        s2[ni] += __shfl_xor(s2[ni], 16); s2[ni] += __shfl_xor(s2[ni], 32);
    }
    if (lane < 16) {
        #pragma unroll
        for (int ni = 0; ni < 8; ni++) { sred[w][ni * 16 + lane] = s[ni]; s2red[w][ni * 16 + lane] = s2[ni]; }
    }
    __syncthreads();
    if (t < 128) {
        bn2s[bid * 128 + t]  = sred[0][t] + sred[1][t] + sred[2][t] + sred[3][t];
        bn2s2[bid * 128 + t] = s2red[0][t] + s2red[1][t] + s2red[2][t] + s2red[3][t];
    }
}

// ---------------- k4a/k4b: reduce BN2 partials -> fused epilogue params ----------------
__global__ __launch_bounds__(256) void k4a(const float* __restrict__ bn2s, const float* __restrict__ bn2s2,
        float* __restrict__ l2s, float* __restrict__ l2s2) {
    int j = blockIdx.x, t = threadIdx.x, c = t & 127, half = t >> 7;
    float s = 0, s2 = 0;
    for (int rr = half; rr < 32; rr += 2) {
        int row = j * 32 + rr;
        s += bn2s[row * 128 + c]; s2 += bn2s2[row * 128 + c];
    }
    __shared__ float red[2][2][128];
    red[0][half][c] = s; red[1][half][c] = s2;
    __syncthreads();
    if (t < 128) { l2s[j * 128 + t] = red[0][0][t] + red[0][1][t]; l2s2[j * 128 + t] = red[1][0][t] + red[1][1][t]; }
}

__global__ __launch_bounds__(128) void k4b(const float* __restrict__ l2s, const float* __restrict__ l2s2,
        const float* __restrict__ gc, const float* __restrict__ betac, const float* __restrict__ bc1,
        float* __restrict__ Af, float* __restrict__ Bf) {
    int c = threadIdx.x;
    float s = 0, s2 = 0;
    #pragma unroll
    for (int j = 0; j < 64; j++) { s += l2s[j * 128 + c]; s2 += l2s2[j * 128 + c]; }
    float inv = 1.f / (float)P_;
    float mean = s * inv, var = s2 * inv - mean * mean;
    float sc = gc[c] * rsqrtf(var + 1e-5f);
    float sh = betac[c] - mean * sc;
    Af[c] = sc;
    Bf[c] = bc1[c] * sc + sh;   // fused: x = acc*Af + Bf
}

// ---------------- k5: fused contact — recompute z tile, BN2+ReLU+Wc2 dot in registers ----------------
__global__ __launch_bounds__(256) void k5_contact(const float* __restrict__ U, const float* __restrict__ V,
        const ushort* __restrict__ wc1T,
        const float* __restrict__ scale1, const float* __restrict__ shift1,
        const float* __restrict__ Af, const float* __restrict__ Bf,
        const float* __restrict__ Wc2, const float* __restrict__ bc2,
        const float* __restrict__ posl, const float* __restrict__ posr,
        float* __restrict__ outc, float* __restrict__ outt) {
    __shared__ ushort hT[128 * LDH];
    __shared__ ushort wT[128 * LDH];
    int bid = blockIdx.x, t = threadIdx.x;
    int i0 = bid * 128;
    int bl = i0 >> 9;
    int vbase = ((bl >> 6) << 9) + (i0 & 511);
    #pragma unroll
    for (int it = 0; it < 8; it++) {
        int chunk = t + it * 256;
        int n = chunk >> 4, ko = (chunk & 15) * 8;
        *(bf16x8*)&wT[n * LDH + ko] = *(const bf16x8*)&wc1T[n * 128 + ko];
    }
    {
        int c4 = (t & 31) * 4, rg = t >> 5;
        float4 uu = *(const float4*)&U[bl * HID + c4];
        float4 sc = *(const float4*)&scale1[c4];
        float4 sh = *(const float4*)&shift1[c4];
        for (int rr = rg; rr < 128; rr += 8) {
            float4 v = *(const float4*)&V[(vbase + rr) * HID + c4];
            u16x4 o;
            o.x = f2bf(elu1((uu.x + v.x) * sc.x + sh.x));
            o.y = f2bf(elu1((uu.y + v.y) * sc.y + sh.y));
            o.z = f2bf(elu1((uu.z + v.z) * sc.z + sh.z));
            o.w = f2bf(elu1((uu.w + v.w) * sc.w + sh.w));
            *(u16x4*)&hT[rr * LDH + c4] = o;
        }
    }
    __syncthreads();
    int w = t >> 6, lane = t & 63;
    int wrow = w * 32, lrow = lane & 15, kgrp = lane >> 4;
    f32x4 acc[2][8];
    #pragma unroll
    for (int mi = 0; mi < 2; mi++)
        #pragma unroll
        for (int ni = 0; ni < 8; ni++) acc[mi][ni] = (f32x4){0.f, 0.f, 0.f, 0.f};
    #pragma unroll
    for (int ks = 0; ks < 4; ks++) {
        int ko = ks * 32 + kgrp * 8;
        bf16x8 a0 = *(const bf16x8*)&hT[(wrow + lrow) * LDH + ko];
        bf16x8 a1 = *(const bf16x8*)&hT[(wrow + 16 + lrow) * LDH + ko];
        #pragma unroll
        for (int ni = 0; ni < 8; ni++) {
            bf16x8 bfr = *(const bf16x8*)&wT[(ni * 16 + lrow) * LDH + ko];
            acc[0][ni] = __builtin_amdgcn_mfma_f32_16x16x32_bf16(a0, bfr, acc[0][ni], 0, 0, 0);
            acc[1][ni] = __builtin_amdgcn_mfma_f32_16x16x32_bf16(a1, bfr, acc[1][ni], 0, 0, 0);
        }
    }
    // fused epilogue: relu(acc*Af + Bf) . Wc2 ; 16-lane shfl reduce per row
    float Asc[8], Bsh[8], Wv[8];
    #pragma unroll
    for (int ni = 0; ni < 8; ni++) {
        int c = ni * 16 + lrow;
        Asc[ni] = Af[c]; Bsh[ni] = Bf[c]; Wv[ni] = Wc2[c];
    }
    float bc2v = bc2[0];
    float pl0 = posl[bl * 3], pl1 = posl[bl * 3 + 1], pl2 = posl[bl * 3 + 2];
    #pragma unroll
    for (int mi = 0; mi < 2; mi++)
        #pragma unroll
        for (int reg = 0; reg < 4; reg++) {
            float s = 0.f;
            #pragma unroll
            for (int ni = 0; ni < 8; ni++) {
                float x = fmaf(acc[mi][ni][reg], Asc[ni], Bsh[ni]);
                s += fmaxf(x, 0.f) * Wv[ni];
            }
            s += __shfl_xor(s, 1); s += __shfl_xor(s, 2); s += __shfl_xor(s, 4); s += __shfl_xor(s, 8);
            if (lrow == 0) {
                int rloc = wrow + mi * 16 + kgrp * 4 + reg;
                int grow = i0 + rloc;
                outc[grow] = s + bc2v;
                int rrow = vbase + rloc;
                float dx = pl0 - posr[rrow * 3];
                float dy = pl1 - posr[rrow * 3 + 1];
                float dz = pl2 - posr[rrow * 3 + 2];
                float y = sqrtf(dx * dx + dy * dy + dz * dz);
                outt[grow] = (y < 8.0f) ? 1.0f : 0.0f;
            }
        }
}

// ---------------- k6: MDN (gather h via U+V recompute, 128x32 MFMA, full epilogue) ----------------
__global__ __launch_bounds__(256) void k6_mdn(const int* __restrict__ mask,
        const float* __restrict__ U, const float* __restrict__ V,
        const float* __restrict__ scale1, const float* __restrict__ shift1,
        const ushort* __restrict__ whg,
        const float* __restrict__ bpi, const float* __restrict__ bsig, const float* __restrict__ bmu,
        const float* __restrict__ posl, const float* __restrict__ posr,
        float* __restrict__ out_logpi, float* __restrict__ out_sigma, float* __restrict__ out_mu,
        float* __restrict__ mdn_psum, float* __restrict__ mdn_pcnt) {
    __shared__ ushort hT[128 * LDH];
    __shared__ ushort wT[32 * LDH];
    __shared__ float zl[128 * 33];
    __shared__ int midx[128];
    __shared__ float mdnv[128];
    __shared__ int mdnb[128];
    int bid = blockIdx.x, t = threadIdx.x;
    int m0 = bid * 128;
    if (t < 128) midx[t] = mask[m0 + t];
    #pragma unroll
    for (int it = 0; it < 2; it++) {
        int chunk = t + it * 256;
        int n = chunk >> 4, ko = (chunk & 15) * 8;
        *(bf16x8*)&wT[n * LDH + ko] = *(const bf16x8*)&whg[n * 128 + ko];
    }
    __syncthreads();
    {
        int c4 = (t & 31) * 4, rg = t >> 5;
        float4 sc = *(const float4*)&scale1[c4];
        float4 sh = *(const float4*)&shift1[c4];
        for (int rr = rg; rr < 128; rr += 8) {
            int i = midx[rr];
            int bl = i >> 9, b = i >> 15, r = i & 511;
            float4 uu = *(const float4*)&U[bl * HID + c4];
            float4 v  = *(const float4*)&V[(b * NR + r) * HID + c4];
            u16x4 o;
            o.x = f2bf(elu1((uu.x + v.x) * sc.x + sh.x));
            o.y = f2bf(elu1((uu.y + v.y) * sc.y + sh.y));
            o.z = f2bf(elu1((uu.z + v.z) * sc.z + sh.z));
            o.w = f2bf(elu1((uu.w + v.w) * sc.w + sh.w));
            *(u16x4*)&hT[rr * LDH + c4] = o;
        }
    }
    __syncthreads();
    int w = t >> 6, lane = t & 63;
    int wrow = w * 32, lrow = lane & 15, kgrp = lane >> 4;
    f32x4 acc[2][2];
    #pragma unroll
    for (int mi = 0; mi < 2; mi++)
        #pragma unroll
        for (int ni = 0; ni < 2; ni++) acc[mi][ni] = (f32x4){0.f, 0.f, 0.f, 0.f};
    #pragma unroll
    for (int ks = 0; ks < 4; ks++) {
        int ko = ks * 32 + kgrp * 8;
        bf16x8 a0 = *(const bf16x8*)&hT[(wrow + lrow) * LDH + ko];
        bf16x8 a1 = *(const bf16x8*)&hT[(wrow + 16 + lrow) * LDH + ko];
        bf16x8 b0 = *(const bf16x8*)&wT[lrow * LDH + ko];
        bf16x8 b1 = *(const bf16x8*)&wT[(16 + lrow) * LDH + ko];
        acc[0][0] = __builtin_amdgcn_mfma_f32_16x16x32_bf16(a0, b0, acc[0][0], 0, 0, 0);
        acc[0][1] = __builtin_amdgcn_mfma_f32_16x16x32_bf16(a0, b1, acc[0][1], 0, 0, 0);
        acc[1][0] = __builtin_amdgcn_mfma_f32_16x16x32_bf16(a1, b0, acc[1][0], 0, 0, 0);
        acc[1][1] = __builtin_amdgcn_mfma_f32_16x16x32_bf16(a1, b1, acc[1][1], 0, 0, 0);
    }
    #pragma unroll
    for (int mi = 0; mi < 2; mi++)
        #pragma unroll
        for (int ni = 0; ni < 2; ni++)
            #pragma unroll
            for (int reg = 0; reg < 4; reg++) {
                int row = wrow + mi * 16 + kgrp * 4 + reg;
                zl[row * 33 + ni * 16 + lrow] = acc[mi][ni][reg];
            }
    __syncthreads();
    if (t < 128) {
        float z[30];
        #pragma unroll
        for (int j = 0; j < 30; j++) z[j] = zl[t * 33 + j];
        float lp[10], mx = -1e30f;
        #pragma unroll
        for (int j = 0; j < 10; j++) { lp[j] = z[j] + bpi[j]; mx = fmaxf(mx, lp[j]); }
        float se = 0.f;
        #pragma unroll
        for (int j = 0; j < 10; j++) se += expf(lp[j] - mx);
        float lse = mx + logf(se);
        #pragma unroll
        for (int j = 0; j < 10; j++) lp[j] -= lse;
        float sg[10], muv[10];
        #pragma unroll
        for (int j = 0; j < 10; j++) sg[j] = elu1(z[10 + j] + bsig[j]) + 1.1f;
        #pragma unroll
        for (int j = 0; j < 10; j++) muv[j] = elu1(z[20 + j] + bmu[j]) + 1.0f;
        int i = midx[t];
        int bl = i >> 9, b = i >> 15, r = i & 511;
        float dx = posl[bl * 3]     - posr[(b * NR + r) * 3];
        float dy = posl[bl * 3 + 1] - posr[(b * NR + r) * 3 + 1];
        float dz = posl[bl * 3 + 2] - posr[(b * NR + r) * 3 + 2];
        float y = sqrtf(dx * dx + dy * dy + dz * dz);
        float tt[10], mm = -1e30f;
        #pragma unroll
        for (int j = 0; j < 10; j++) {
            float q = (y - muv[j]) / sg[j];
            float llv = -0.5f * q * q - logf(sg[j]) - 0.91893853320467274f;
            tt[j] = lp[j] + llv; mm = fmaxf(mm, tt[j]);
        }
        float s2e = 0.f;
        #pragma unroll
        for (int j = 0; j < 10; j++) s2e += expf(tt[j] - mm);
        float mdn = -(mm + logf(s2e));
        int mrow = m0 + t;
        #pragma unroll
        for (int j = 0; j < 10; j++) out_logpi[mrow * 10 + j] = lp[j];
        #pragma unroll
        for (int j = 0; j < 10; j++) out_sigma[mrow * 10 + j] = sg[j];
        #pragma unroll
        for (int j = 0; j < 10; j++) out_mu[mrow * 10 + j] = muv[j];
        mdnv[t] = mdn; mdnb[t] = b;
    }
    __syncthreads();
    if (t < 8) {  // deterministic fixed-order per-batch partial sums
        float s = 0.f; int cnt = 0;
        for (int rr = 0; rr < 128; rr++) if (mdnb[rr] == t) { s += mdnv[rr]; cnt++; }
        mdn_psum[bid * 8 + t] = s; mdn_pcnt[bid * 8 + t] = (float)cnt;
    }
}

// ---------------- k7: prob = segment mean ----------------
__global__ __launch_bounds__(256) void k7_prob(const float* __restrict__ psum, const float* __restrict__ pcnt,
        float* __restrict__ prob) {
    int b = blockIdx.x, t = threadIdx.x;
    float s = 0, c = 0;
    for (int idx = t; idx < 1024; idx += 256) { s += psum[idx * 8 + b]; c += pcnt[idx * 8 + b]; }
    __shared__ float rs[256], rc[256];
    rs[t] = s; rc[t] = c;
    __syncthreads();
    for (int off = 128; off > 0; off >>= 1) {
        if (t < off) { rs[t] += rs[t + off]; rc[t] += rc[t + off]; }
        __syncthreads();
    }
    if (t == 0) prob[b] = rs[0] / fmaxf(rc[0], 1.f);
}

extern "C" void kernel_launch(void* const* d_in, const int* in_sizes, int n_in,
                              void* d_out, int out_size, void* d_ws, size_t ws_size,
                              hipStream_t stream) {
    const float* flig  = (const float*)d_in[0];
    const float* posl  = (const float*)d_in[1];
    const float* frec  = (const float*)d_in[3];
    const float* posr  = (const float*)d_in[4];
    const int*   mask  = (const int*)d_in[6];
    const float* W1    = (const float*)d_in[7];
    const float* b1    = (const float*)d_in[8];
    const float* g1    = (const float*)d_in[9];
    const float* beta1 = (const float*)d_in[10];
    const float* Wpi   = (const float*)d_in[11];
    const float* bpi   = (const float*)d_in[12];
    const float* Wsig  = (const float*)d_in[13];
    const float* bsig  = (const float*)d_in[14];
    const float* Wmu   = (const float*)d_in[15];
    const float* bmu   = (const float*)d_in[16];
    const float* Wc1   = (const float*)d_in[17];
    const float* bc1   = (const float*)d_in[18];
    const float* gc    = (const float*)d_in[19];
    const float* betac = (const float*)d_in[20];
    const float* Wc2   = (const float*)d_in[21];
    const float* bc2   = (const float*)d_in[22];

    float* ws = (float*)d_ws;
    float* U      = ws;                 // 65536
    float* V      = ws + 65536;         // 524288 (end 589824)
    float* partS  = ws + 589824;        // 576*128 = 73728
    float* partS2 = ws + 663552;        // 73728 (end 737280)
    float* SU     = ws + 737280;        // 1024
    float* SU2    = ws + 738304;
    float* SV     = ws + 739328;
    float* SV2    = ws + 740352;        // (end 741376)
    float* scale1 = ws + 741376;        // 128
    float* shift1 = ws + 741504;
    float* Af     = ws + 741632;
    float* Bf     = ws + 741760;        // (end 741888)
    float* bn2s   = ws + 741888;        // 2048*128 (end 1004032)
    float* bn2s2  = ws + 1004032;       // 2048*128 (end 1266176)
    float* l2s    = ws + 1266176;       // 8192
    float* l2s2   = ws + 1274368;       // (end 1282560)
    float* psum   = ws + 1282560;       // 8192
    float* pcnt   = ws + 1290752;       // (end 1298944)
    ushort* wc1T  = (ushort*)(ws + 1298944);  // 16384 bf16 (8192 f)
    ushort* whg   = (ushort*)(ws + 1307136);  // 4096 bf16 (2048 f)

    float* out = (float*)d_out;
    float* out_logpi   = out;
    float* out_sigma   = out + 1310720;
    float* out_mu      = out + 2621440;
    float* out_prob    = out + 3932160;
    float* out_contact = out + 3932168;
    float* out_truth   = out + 4194312;

    k0_prep<<<dim3(1), dim3(256), 0, stream>>>(Wc1, Wpi, Wsig, Wmu, wc1T, whg);
    k1_uv<<<dim3(576), dim3(128), 0, stream>>>(flig, frec, W1, b1, U, V, partS, partS2);
    k2a<<<dim3(8), dim3(256), 0, stream>>>(partS, partS2, SU, SU2, SV, SV2);
    k2b<<<dim3(1), dim3(128), 0, stream>>>(SU, SU2, SV, SV2, g1, beta1, scale1, shift1);
    k3_stats<<<dim3(2048), dim3(256), 0, stream>>>(U, V, wc1T, bc1, scale1, shift1, bn2s, bn2s2);
    k4a<<<dim3(64), dim3(256), 0, stream>>>(bn2s, bn2s2, l2s, l2s2);
    k4b<<<dim3(1), dim3(128), 0, stream>>>(l2s, l2s2, gc, betac, bc1, Af, Bf);
    k5_contact<<<dim3(2048), dim3(256), 0, stream>>>(U, V, wc1T, scale1, shift1, Af, Bf, Wc2, bc2,
        posl, posr, out_contact, out_truth);
    k6_mdn<<<dim3(1024), dim3(256), 0, stream>>>(mask, U, V, scale1, shift1, whg,
        bpi, bsig, bmu, posl, posr, out_logpi, out_sigma, out_mu, psum, pcnt);
    k7_prob<<<dim3(8), dim3(256), 0, stream>>>(psum, pcnt, out_prob);
}

// Round 3
// 123.808 us; speedup vs baseline: 1.9826x; 1.5323x over previous
//
#include <hip/hip_runtime.h>
#include <math.h>

#define B_ 8
#define NL 64
#define NR 512
#define FD 128
#define HID 128
#define KM 10
#define P_ 262144
#define M_ 131072
#define LDH 136   // padded LDS row stride in bf16 elems (272B, breaks bank conflicts)

typedef short bf16x8 __attribute__((ext_vector_type(8)));
typedef float f32x4 __attribute__((ext_vector_type(4)));

static __device__ __forceinline__ ushort f2bf(float x) {
    union { float f; unsigned int u; } v; v.f = x;
    unsigned int r = v.u + 0x7FFFu + ((v.u >> 16) & 1u);
    return (ushort)(r >> 16);
}
static __device__ __forceinline__ float bf2f(ushort s) {
    union { unsigned int u; float f; } v; v.u = ((unsigned int)s) << 16;
    return v.f;
}
static __device__ __forceinline__ float elu1(float x) {
    return x > 0.f ? x : (__expf(x) - 1.f);
}

// ---------------- k0: pre-swizzle weights into MFMA B-fragment order ----------------
// fragment element e = ((ni*4+ks)*64 + lane)*8 + j  maps to  col n=ni*16+(lane&15), k=ks*32+(lane>>4)*8+j
__global__ __launch_bounds__(256) void k0_prep(const float* __restrict__ Wc1,
        const float* __restrict__ Wpi, const float* __restrict__ Wsig, const float* __restrict__ Wmu,
        ushort* __restrict__ wB, ushort* __restrict__ wBg) {
    int t = threadIdx.x;
    for (int idx = t; idx < 16384; idx += 256) {
        int j = idx & 7, lane = (idx >> 3) & 63, ks = (idx >> 9) & 3, ni = idx >> 11;
        int lrow = lane & 15, kgrp = lane >> 4;
        int n = ni * 16 + lrow, k = ks * 32 + kgrp * 8 + j;
        wB[idx] = f2bf(Wc1[k * HID + n]);
    }
    for (int idx = t; idx < 4096; idx += 256) {
        int j = idx & 7, lane = (idx >> 3) & 63, ks = (idx >> 9) & 3, ni = (idx >> 11) & 1;
        int lrow = lane & 15, kgrp = lane >> 4;
        int n = ni * 16 + lrow, k = ks * 32 + kgrp * 8 + j;
        float wv = 0.f;
        if (n < 10) wv = Wpi[k * KM + n];
        else if (n < 20) wv = Wsig[k * KM + (n - 10)];
        else if (n < 30) wv = Wmu[k * KM + (n - 20)];
        wBg[idx] = f2bf(wv);
    }
}

// ---------------- k1: U = flig @ W1_top + b1 ; V = frec @ W1_bot ; emit col partials ----------------
__global__ __launch_bounds__(128) void k1_uv(const float* __restrict__ flig,
        const float* __restrict__ frec, const float* __restrict__ W1,
        const float* __restrict__ b1, float* __restrict__ U, float* __restrict__ V,
        float* __restrict__ partS, float* __restrict__ partS2) {
    __shared__ float fr[8][128];
    int bid = blockIdx.x, c = threadIdx.x;
    const float* feat; const float* Wb; float* outp; float bias;
    if (bid < 64) {
        int rowbase = bid * 8;
        feat = flig + rowbase * FD; Wb = W1; outp = U + rowbase * HID; bias = b1[c];
    } else {
        int rowbase = (bid - 64) * 8;
        feat = frec + rowbase * FD; Wb = W1 + FD * HID; outp = V + rowbase * HID; bias = 0.f;
    }
    #pragma unroll
    for (int rr = 0; rr < 8; rr++) fr[rr][c] = feat[rr * FD + c];
    __syncthreads();
    float acc[8];
    #pragma unroll
    for (int rr = 0; rr < 8; rr++) acc[rr] = bias;
    #pragma unroll 4
    for (int k = 0; k < FD; k++) {
        float wv = Wb[k * HID + c];
        #pragma unroll
        for (int rr = 0; rr < 8; rr++) acc[rr] += fr[rr][k] * wv;
    }
    float su = 0.f, su2 = 0.f;
    #pragma unroll
    for (int rr = 0; rr < 8; rr++) {
        outp[rr * HID + c] = acc[rr];
        su += acc[rr]; su2 += acc[rr] * acc[rr];
    }
    partS[bid * 128 + c] = su;
    partS2[bid * 128 + c] = su2;
}

// ---------------- k2a: per-batch reduce of partials ----------------
__global__ __launch_bounds__(256) void k2a(const float* __restrict__ partS, const float* __restrict__ partS2,
        float* __restrict__ SU, float* __restrict__ SU2, float* __restrict__ SV, float* __restrict__ SV2) {
    int b = blockIdx.x, t = threadIdx.x, c = t & 127, half = t >> 7;
    if (half == 0) {
        float s = 0.f, s2 = 0.f;
        #pragma unroll
        for (int j = 0; j < 8; j++) { int row = b * 8 + j; s += partS[row * 128 + c]; s2 += partS2[row * 128 + c]; }
        SU[b * 128 + c] = s; SU2[b * 128 + c] = s2;
    } else {
        float s = 0.f, s2 = 0.f;
        for (int j = 0; j < 64; j++) { int row = 64 + b * 64 + j; s += partS[row * 128 + c]; s2 += partS2[row * 128 + c]; }
        SV[b * 128 + c] = s; SV2[b * 128 + c] = s2;
    }
}

// ---------------- k2b: finalize BN1 scale/shift ----------------
__global__ __launch_bounds__(128) void k2b(const float* __restrict__ SU, const float* __restrict__ SU2,
        const float* __restrict__ SV, const float* __restrict__ SV2,
        const float* __restrict__ g1, const float* __restrict__ beta1,
        float* __restrict__ scale1, float* __restrict__ shift1) {
    int c = threadIdx.x;
    float sum = 0.f, ssq = 0.f;
    #pragma unroll
    for (int b = 0; b < B_; b++) {
        float su = SU[b * 128 + c], sv = SV[b * 128 + c];
        sum += (float)NR * su + (float)NL * sv;
        ssq += (float)NR * SU2[b * 128 + c] + 2.f * su * sv + (float)NL * SV2[b * 128 + c];
    }
    float inv = 1.f / (float)P_;
    float mean = sum * inv;
    float var = ssq * inv - mean * mean;
    float sc = g1[c] * rsqrtf(var + 1e-5f);
    scale1[c] = sc; shift1[c] = beta1[c] - mean * sc;
}

// ---------------- k3: z = h @ Wc1 + bc1 -> store bf16 z + BN2 col stats ----------------
__global__ __launch_bounds__(256) void k3_stats(const float* __restrict__ U, const float* __restrict__ V,
        const ushort* __restrict__ wB, const float* __restrict__ bc1,
        const float* __restrict__ scale1, const float* __restrict__ shift1,
        ushort* __restrict__ z, float* __restrict__ bn2s, float* __restrict__ bn2s2) {
    __shared__ ushort hT[128 * LDH];
    __shared__ float sred[4][128];
    __shared__ float s2red[4][128];
    int bid = blockIdx.x, t = threadIdx.x;
    int i0 = bid * 128;
    int bl = i0 >> 9;
    int vbase = ((bl >> 6) << 9) + (i0 & 511);
    // stage h tile: h = elu((U+V)*scale1 + shift1); 8 cols/thread, b128 LDS writes
    {
        int c8 = (t & 15) * 8, rg = t >> 4;
        float4 u0 = *(const float4*)&U[bl * HID + c8];
        float4 u1 = *(const float4*)&U[bl * HID + c8 + 4];
        float4 sc0 = *(const float4*)&scale1[c8], sc1 = *(const float4*)&scale1[c8 + 4];
        float4 sh0 = *(const float4*)&shift1[c8], sh1 = *(const float4*)&shift1[c8 + 4];
        #pragma unroll
        for (int rr = rg; rr < 128; rr += 16) {
            const float* vp = &V[(vbase + rr) * HID + c8];
            float4 v0 = *(const float4*)vp, v1 = *(const float4*)(vp + 4);
            union { bf16x8 v; ushort u[8]; } o;
            o.u[0] = f2bf(elu1(fmaf(u0.x + v0.x, sc0.x, sh0.x)));
            o.u[1] = f2bf(elu1(fmaf(u0.y + v0.y, sc0.y, sh0.y)));
            o.u[2] = f2bf(elu1(fmaf(u0.z + v0.z, sc0.z, sh0.z)));
            o.u[3] = f2bf(elu1(fmaf(u0.w + v0.w, sc0.w, sh0.w)));
            o.u[4] = f2bf(elu1(fmaf(u1.x + v1.x, sc1.x, sh1.x)));
            o.u[5] = f2bf(elu1(fmaf(u1.y + v1.y, sc1.y, sh1.y)));
            o.u[6] = f2bf(elu1(fmaf(u1.z + v1.z, sc1.z, sh1.z)));
            o.u[7] = f2bf(elu1(fmaf(u1.w + v1.w, sc1.w, sh1.w)));
            *(bf16x8*)&hT[rr * LDH + c8] = o.v;
        }
    }
    __syncthreads();
    int w = t >> 6, lane = t & 63;
    int wrow = w * 32, lrow = lane & 15, kgrp = lane >> 4;
    f32x4 acc[2][8];
    #pragma unroll
    for (int mi = 0; mi < 2; mi++)
        #pragma unroll
        for (int ni = 0; ni < 8; ni++) acc[mi][ni] = (f32x4){0.f, 0.f, 0.f, 0.f};
    const bf16x8* wBv = (const bf16x8*)wB;
    #pragma unroll
    for (int ks = 0; ks < 4; ks++) {
        int ko = ks * 32 + kgrp * 8;
        bf16x8 a0 = *(const bf16x8*)&hT[(wrow + lrow) * LDH + ko];
        bf16x8 a1 = *(const bf16x8*)&hT[(wrow + 16 + lrow) * LDH + ko];
        #pragma unroll
        for (int ni = 0; ni < 8; ni++) {
            bf16x8 bfr = wBv[(ni * 4 + ks) * 64 + lane];
            acc[0][ni] = __builtin_amdgcn_mfma_f32_16x16x32_bf16(a0, bfr, acc[0][ni], 0, 0, 0);
            acc[1][ni] = __builtin_amdgcn_mfma_f32_16x16x32_bf16(a1, bfr, acc[1][ni], 0, 0, 0);
        }
    }
    // bias + stats + z-stage into own LDS rows (wave-local, no barrier needed)
    float s[8], s2[8];
    #pragma unroll
    for (int ni = 0; ni < 8; ni++) {
        float bcv = bc1[ni * 16 + lrow];
        s[ni] = 0.f; s2[ni] = 0.f;
        #pragma unroll
        for (int mi = 0; mi < 2; mi++)
            #pragma unroll
            for (int reg = 0; reg < 4; reg++) {
                float vv = acc[mi][ni][reg] + bcv;
                s[ni] += vv; s2[ni] += vv * vv;
                hT[(wrow + mi * 16 + kgrp * 4 + reg) * LDH + ni * 16 + lrow] = f2bf(vv);
            }
    }
    // coalesced copy-out of this wave's 32 z rows
    #pragma unroll
    for (int it = 0; it < 8; it++) {
        int chunk = lane + it * 64;
        int row = wrow + (chunk >> 4), cc = (chunk & 15) * 8;
        *(bf16x8*)&z[(i0 + row) * HID + cc] = *(const bf16x8*)&hT[row * LDH + cc];
    }
    #pragma unroll
    for (int ni = 0; ni < 8; ni++) {
        s[ni] += __shfl_xor(s[ni], 16);  s[ni] += __shfl_xor(s[ni], 32);
        s2[ni] += __shfl_xor(s2[ni], 16); s2[ni] += __shfl_xor(s2[ni], 32);
    }
    if (lane < 16) {
        #pragma unroll
        for (int ni = 0; ni < 8; ni++) { sred[w][ni * 16 + lane] = s[ni]; s2red[w][ni * 16 + lane] = s2[ni]; }
    }
    __syncthreads();
    if (t < 128) {
        bn2s[bid * 128 + t]  = sred[0][t] + sred[1][t] + sred[2][t] + sred[3][t];
        bn2s2[bid * 128 + t] = s2red[0][t] + s2red[1][t] + s2red[2][t] + s2red[3][t];
    }
}

// ---------------- k4a/k4b: reduce BN2 partials -> fused epilogue params ----------------
__global__ __launch_bounds__(256) void k4a(const float* __restrict__ bn2s, const float* __restrict__ bn2s2,
        float* __restrict__ l2s, float* __restrict__ l2s2) {
    int j = blockIdx.x, t = threadIdx.x, c = t & 127, half = t >> 7;
    float s = 0, s2 = 0;
    for (int rr = half; rr < 32; rr += 2) {
        int row = j * 32 + rr;
        s += bn2s[row * 128 + c]; s2 += bn2s2[row * 128 + c];
    }
    __shared__ float red[2][2][128];
    red[0][half][c] = s; red[1][half][c] = s2;
    __syncthreads();
    if (t < 128) { l2s[j * 128 + t] = red[0][0][t] + red[0][1][t]; l2s2[j * 128 + t] = red[1][0][t] + red[1][1][t]; }
}

__global__ __launch_bounds__(128) void k4b(const float* __restrict__ l2s, const float* __restrict__ l2s2,
        const float* __restrict__ gc, const float* __restrict__ betac,
        float* __restrict__ Af, float* __restrict__ Bf) {
    int c = threadIdx.x;
    float s = 0, s2 = 0;
    #pragma unroll
    for (int j = 0; j < 64; j++) { s += l2s[j * 128 + c]; s2 += l2s2[j * 128 + c]; }
    float inv = 1.f / (float)P_;
    float mean = s * inv, var = s2 * inv - mean * mean;
    float sc = gc[c] * rsqrtf(var + 1e-5f);
    Af[c] = sc;
    Bf[c] = betac[c] - mean * sc;   // z already contains bc1
}

// ---------------- k5: streaming contact epilogue over stored z ----------------
__global__ __launch_bounds__(256) void k5_contact(const ushort* __restrict__ z,
        const float* __restrict__ Af, const float* __restrict__ Bf,
        const float* __restrict__ Wc2, const float* __restrict__ bc2,
        const float* __restrict__ posl, const float* __restrict__ posr,
        float* __restrict__ outc, float* __restrict__ outt) {
    __shared__ float sA[128], sB[128], sW[128];
    int bid = blockIdx.x, t = threadIdx.x;
    if (t < 128) { sA[t] = Af[t]; sB[t] = Bf[t]; sW[t] = Wc2[t]; }
    float bc2v = bc2[0];
    __syncthreads();
    int c8 = (t & 15) * 8;
    float a0v[8], b0v[8], w0v[8];
    #pragma unroll
    for (int e = 0; e < 8; e++) { a0v[e] = sA[c8 + e]; b0v[e] = sB[c8 + e]; w0v[e] = sW[c8 + e]; }
    #pragma unroll 2
    for (int it = 0; it < 8; it++) {
        int row = (bid + it * 2048) * 16 + (t >> 4);
        bf16x8 v = *(const bf16x8*)&z[row * HID + c8];
        float s = 0.f;
        #pragma unroll
        for (int e = 0; e < 8; e++) {
            float x = fmaf(bf2f((ushort)v[e]), a0v[e], b0v[e]);
            s += fmaxf(x, 0.f) * w0v[e];
        }
        s += __shfl_xor(s, 1); s += __shfl_xor(s, 2); s += __shfl_xor(s, 4); s += __shfl_xor(s, 8);
        if ((t & 15) == 0) {
            outc[row] = s + bc2v;
            int bl = row >> 9, b = row >> 15, r = row & 511;
            float dx = posl[bl * 3]     - posr[(b * NR + r) * 3];
            float dy = posl[bl * 3 + 1] - posr[(b * NR + r) * 3 + 1];
            float dz = posl[bl * 3 + 2] - posr[(b * NR + r) * 3 + 2];
            float y = sqrtf(dx * dx + dy * dy + dz * dz);
            outt[row] = (y < 8.0f) ? 1.0f : 0.0f;
        }
    }
}

// ---------------- k6: MDN (gather h via U+V recompute, 128x32 MFMA, full epilogue) ----------------
__global__ __launch_bounds__(256) void k6_mdn(const int* __restrict__ mask,
        const float* __restrict__ U, const float* __restrict__ V,
        const float* __restrict__ scale1, const float* __restrict__ shift1,
        const ushort* __restrict__ wBg,
        const float* __restrict__ bpi, const float* __restrict__ bsig, const float* __restrict__ bmu,
        const float* __restrict__ posl, const float* __restrict__ posr,
        float* __restrict__ out_logpi, float* __restrict__ out_sigma, float* __restrict__ out_mu,
        float* __restrict__ mdn_psum, float* __restrict__ mdn_pcnt) {
    __shared__ ushort hT[128 * LDH];
    float* zl = (float*)hT;               // aliased scratch (barriers guard reuse)
    __shared__ int midx[128];
    __shared__ float mdnv[128];
    __shared__ int mdnb[128];
    int bid = blockIdx.x, t = threadIdx.x;
    int m0 = bid * 128;
    if (t < 128) midx[t] = mask[m0 + t];
    __syncthreads();
    {
        int c8 = (t & 15) * 8, rg = t >> 4;
        float4 sc0 = *(const float4*)&scale1[c8], sc1 = *(const float4*)&scale1[c8 + 4];
        float4 sh0 = *(const float4*)&shift1[c8], sh1 = *(const float4*)&shift1[c8 + 4];
        #pragma unroll
        for (int rr = rg; rr < 128; rr += 16) {
            int i = midx[rr];
            int bl = i >> 9, b = i >> 15, r = i & 511;
            const float* up = &U[bl * HID + c8];
            const float* vp = &V[(b * NR + r) * HID + c8];
            float4 u0 = *(const float4*)up, u1 = *(const float4*)(up + 4);
            float4 v0 = *(const float4*)vp, v1 = *(const float4*)(vp + 4);
            union { bf16x8 v; ushort u[8]; } o;
            o.u[0] = f2bf(elu1(fmaf(u0.x + v0.x, sc0.x, sh0.x)));
            o.u[1] = f2bf(elu1(fmaf(u0.y + v0.y, sc0.y, sh0.y)));
            o.u[2] = f2bf(elu1(fmaf(u0.z + v0.z, sc0.z, sh0.z)));
            o.u[3] = f2bf(elu1(fmaf(u0.w + v0.w, sc0.w, sh0.w)));
            o.u[4] = f2bf(elu1(fmaf(u1.x + v1.x, sc1.x, sh1.x)));
            o.u[5] = f2bf(elu1(fmaf(u1.y + v1.y, sc1.y, sh1.y)));
            o.u[6] = f2bf(elu1(fmaf(u1.z + v1.z, sc1.z, sh1.z)));
            o.u[7] = f2bf(elu1(fmaf(u1.w + v1.w, sc1.w, sh1.w)));
            *(bf16x8*)&hT[rr * LDH + c8] = o.v;
        }
    }
    __syncthreads();
    int w = t >> 6, lane = t & 63;
    int wrow = w * 32, lrow = lane & 15, kgrp = lane >> 4;
    f32x4 acc[2][2];
    #pragma unroll
    for (int mi = 0; mi < 2; mi++)
        #pragma unroll
        for (int ni = 0; ni < 2; ni++) acc[mi][ni] = (f32x4){0.f, 0.f, 0.f, 0.f};
    const bf16x8* wBv = (const bf16x8*)wBg;
    #pragma unroll
    for (int ks = 0; ks < 4; ks++) {
        int ko = ks * 32 + kgrp * 8;
        bf16x8 a0 = *(const bf16x8*)&hT[(wrow + lrow) * LDH + ko];
        bf16x8 a1 = *(const bf16x8*)&hT[(wrow + 16 + lrow) * LDH + ko];
        bf16x8 b0 = wBv[ks * 64 + lane];
        bf16x8 b1 = wBv[(4 + ks) * 64 + lane];
        acc[0][0] = __builtin_amdgcn_mfma_f32_16x16x32_bf16(a0, b0, acc[0][0], 0, 0, 0);
        acc[0][1] = __builtin_amdgcn_mfma_f32_16x16x32_bf16(a0, b1, acc[0][1], 0, 0, 0);
        acc[1][0] = __builtin_amdgcn_mfma_f32_16x16x32_bf16(a1, b0, acc[1][0], 0, 0, 0);
        acc[1][1] = __builtin_amdgcn_mfma_f32_16x16x32_bf16(a1, b1, acc[1][1], 0, 0, 0);
    }
    __syncthreads();   // all hT reads done before zl alias writes
    #pragma unroll
    for (int mi = 0; mi < 2; mi++)
        #pragma unroll
        for (int ni = 0; ni < 2; ni++)
            #pragma unroll
            for (int reg = 0; reg < 4; reg++) {
                int row = wrow + mi * 16 + kgrp * 4 + reg;
                zl[row * 33 + ni * 16 + lrow] = acc[mi][ni][reg];
            }
    __syncthreads();
    if (t < 128) {
        float zv[30];
        #pragma unroll
        for (int j = 0; j < 30; j++) zv[j] = zl[t * 33 + j];
        float lp[10], mx = -1e30f;
        #pragma unroll
        for (int j = 0; j < 10; j++) { lp[j] = zv[j] + bpi[j]; mx = fmaxf(mx, lp[j]); }
        float se = 0.f;
        #pragma unroll
        for (int j = 0; j < 10; j++) se += __expf(lp[j] - mx);
        float lse = mx + __logf(se);
        #pragma unroll
        for (int j = 0; j < 10; j++) lp[j] -= lse;
        float sg[10], muv[10];
        #pragma unroll
        for (int j = 0; j < 10; j++) sg[j] = elu1(zv[10 + j] + bsig[j]) + 1.1f;
        #pragma unroll
        for (int j = 0; j < 10; j++) muv[j] = elu1(zv[20 + j] + bmu[j]) + 1.0f;
        int i = midx[t];
        int bl = i >> 9, b = i >> 15, r = i & 511;
        float dx = posl[bl * 3]     - posr[(b * NR + r) * 3];
        float dy = posl[bl * 3 + 1] - posr[(b * NR + r) * 3 + 1];
        float dz = posl[bl * 3 + 2] - posr[(b * NR + r) * 3 + 2];
        float y = sqrtf(dx * dx + dy * dy + dz * dz);
        float tt[10], mm = -1e30f;
        #pragma unroll
        for (int j = 0; j < 10; j++) {
            float q = (y - muv[j]) / sg[j];
            float llv = -0.5f * q * q - __logf(sg[j]) - 0.91893853320467274f;
            tt[j] = lp[j] + llv; mm = fmaxf(mm, tt[j]);
        }
        float s2e = 0.f;
        #pragma unroll
        for (int j = 0; j < 10; j++) s2e += __expf(tt[j] - mm);
        float mdn = -(mm + __logf(s2e));
        int mrow = m0 + t;
        #pragma unroll
        for (int j = 0; j < 10; j++) out_logpi[mrow * 10 + j] = lp[j];
        #pragma unroll
        for (int j = 0; j < 10; j++) out_sigma[mrow * 10 + j] = sg[j];
        #pragma unroll
        for (int j = 0; j < 10; j++) out_mu[mrow * 10 + j] = muv[j];
        mdnv[t] = mdn; mdnb[t] = b;
    }
    __syncthreads();
    if (t < 8) {  // deterministic fixed-order per-batch partial sums
        float s = 0.f; int cnt = 0;
        for (int rr = 0; rr < 128; rr++) if (mdnb[rr] == t) { s += mdnv[rr]; cnt++; }
        mdn_psum[bid * 8 + t] = s; mdn_pcnt[bid * 8 + t] = (float)cnt;
    }
}

// ---------------- k7: prob = segment mean ----------------
__global__ __launch_bounds__(256) void k7_prob(const float* __restrict__ psum, const float* __restrict__ pcnt,
        float* __restrict__ prob) {
    int b = blockIdx.x, t = threadIdx.x;
    float s = 0, c = 0;
    for (int idx = t; idx < 1024; idx += 256) { s += psum[idx * 8 + b]; c += pcnt[idx * 8 + b]; }
    __shared__ float rs[256], rc[256];
    rs[t] = s; rc[t] = c;
    __syncthreads();
    for (int off = 128; off > 0; off >>= 1) {
        if (t < off) { rs[t] += rs[t + off]; rc[t] += rc[t + off]; }
        __syncthreads();
    }
    if (t == 0) prob[b] = rs[0] / fmaxf(rc[0], 1.f);
}

extern "C" void kernel_launch(void* const* d_in, const int* in_sizes, int n_in,
                              void* d_out, int out_size, void* d_ws, size_t ws_size,
                              hipStream_t stream) {
    const float* flig  = (const float*)d_in[0];
    const float* posl  = (const float*)d_in[1];
    const float* frec  = (const float*)d_in[3];
    const float* posr  = (const float*)d_in[4];
    const int*   mask  = (const int*)d_in[6];
    const float* W1    = (const float*)d_in[7];
    const float* b1    = (const float*)d_in[8];
    const float* g1    = (const float*)d_in[9];
    const float* beta1 = (const float*)d_in[10];
    const float* Wpi   = (const float*)d_in[11];
    const float* bpi   = (const float*)d_in[12];
    const float* Wsig  = (const float*)d_in[13];
    const float* bsig  = (const float*)d_in[14];
    const float* Wmu   = (const float*)d_in[15];
    const float* bmu   = (const float*)d_in[16];
    const float* Wc1   = (const float*)d_in[17];
    const float* bc1   = (const float*)d_in[18];
    const float* gc    = (const float*)d_in[19];
    const float* betac = (const float*)d_in[20];
    const float* Wc2   = (const float*)d_in[21];
    const float* bc2   = (const float*)d_in[22];

    float* ws = (float*)d_ws;
    float* U      = ws;                 // 65536
    float* V      = ws + 65536;         // 524288 (end 589824)
    float* scale1 = ws + 589824;        // 128
    float* shift1 = ws + 589952;
    float* Af     = ws + 590080;
    float* Bf     = ws + 590208;        // (end 590336)
    float* SU     = ws + 590336;        // 1024
    float* SU2    = ws + 591360;
    float* SV     = ws + 592384;
    float* SV2    = ws + 593408;        // (end 594432)
    ushort* wB    = (ushort*)(ws + 594432);   // 16384 bf16 = 8192 f (end 602624)
    ushort* wBg   = (ushort*)(ws + 602624);   // 4096 bf16 = 2048 f (end 604672)
    float* bn2s   = ws + 604672;        // 2048*128 (end 866816)
    float* bn2s2  = ws + 866816;        // (end 1128960)
    float* psum   = ws + 1128960;       // 8192 (end 1137152)
    float* pcnt   = ws + 1137152;       // (end 1145344)
    ushort* zbuf  = (ushort*)(ws + 1145344);  // P*128 bf16 = 67.1 MB
    // partS/partS2 alias the zbuf region: dead before k3 writes z (stream-ordered)
    float* partS  = ws + 1145344;       // 576*128 = 73728
    float* partS2 = ws + 1219072;       // 73728 (end 1292800)
    // l2s/l2s2 live only between k4a and k4b; reuse SU area is too small -> place after pcnt? use psum area? keep separate small
    float* l2s    = ws + 590336 - 0;    // NOTE: replaced below
    (void)l2s;
    float* l2sA   = ws + 594432 - 0;    // placeholder
    (void)l2sA;
    // dedicated small region for l2s/l2s2 inside zbuf-alias space after partS2 (dead before k3? NO - needed after k3)
    // put them in the bn2s tail? bn2s is still live. Use fresh slots after pcnt but before zbuf start? zbuf starts 1145344.
    // psum/pcnt written by k6 (after k4). l2s/l2s2 are 128*64 each = 8192+8192 -> carve from SU region? SU dead after k2b.
    float* l2s_   = SU;    // 8192 needed, SU..SV2 region is 4096 floats only -> instead reuse bn2s2 tail is live...
    (void)l2s_;
    // Simplest correct choice: l2s/l2s2 into psum/pcnt region (psum/pcnt written later by k6, read by k7 after k6;
    // l2s is read by k4b BEFORE k6 runs). Lifetimes: l2s [k4a..k4b], psum [k6..k7] -> disjoint, safe to share.
    float* l2s2_  = pcnt;
    float* l2s1_  = psum;

    float* out = (float*)d_out;
    float* out_logpi   = out;
    float* out_sigma   = out + 1310720;
    float* out_mu      = out + 2621440;
    float* out_prob    = out + 3932160;
    float* out_contact = out + 3932168;
    float* out_truth   = out + 4194312;

    k0_prep<<<dim3(1), dim3(256), 0, stream>>>(Wc1, Wpi, Wsig, Wmu, wB, wBg);
    k1_uv<<<dim3(576), dim3(128), 0, stream>>>(flig, frec, W1, b1, U, V, partS, partS2);
    k2a<<<dim3(8), dim3(256), 0, stream>>>(partS, partS2, SU, SU2, SV, SV2);
    k2b<<<dim3(1), dim3(128), 0, stream>>>(SU, SU2, SV, SV2, g1, beta1, scale1, shift1);
    k3_stats<<<dim3(2048), dim3(256), 0, stream>>>(U, V, wB, bc1, scale1, shift1, zbuf, bn2s, bn2s2);
    k4a<<<dim3(64), dim3(256), 0, stream>>>(bn2s, bn2s2, l2s1_, l2s2_);
    k4b<<<dim3(1), dim3(128), 0, stream>>>(l2s1_, l2s2_, gc, betac, Af, Bf);
    k5_contact<<<dim3(2048), dim3(256), 0, stream>>>(zbuf, Af, Bf, Wc2, bc2, posl, posr, out_contact, out_truth);
    k6_mdn<<<dim3(1024), dim3(256), 0, stream>>>(mask, U, V, scale1, shift1, wBg,
        bpi, bsig, bmu, posl, posr, out_logpi, out_sigma, out_mu, psum, pcnt);
    k7_prob<<<dim3(8), dim3(256), 0, stream>>>(psum, pcnt, out_prob);
}

// Round 4
// 118.579 us; speedup vs baseline: 2.0700x; 1.0441x over previous
//
#include <hip/hip_runtime.h>
#include <math.h>

#define B_ 8
#define NL 64
#define NR 512
#define FD 128
#define HID 128
#define KM 10
#define P_ 262144
#define M_ 131072
#define LDH 136   // padded LDS row stride in bf16 elems (272B, breaks bank conflicts)

typedef short bf16x8 __attribute__((ext_vector_type(8)));
typedef float f32x4 __attribute__((ext_vector_type(4)));

static __device__ __forceinline__ ushort f2bf(float x) {
    union { float f; unsigned int u; } v; v.f = x;
    unsigned int r = v.u + 0x7FFFu + ((v.u >> 16) & 1u);
    return (ushort)(r >> 16);
}
static __device__ __forceinline__ float bf2f(ushort s) {
    union { unsigned int u; float f; } v; v.u = ((unsigned int)s) << 16;
    return v.f;
}
static __device__ __forceinline__ float elu1(float x) {
    return x > 0.f ? x : (__expf(x) - 1.f);
}

// ---------------- k0: pre-swizzle weights into MFMA B-fragment order ----------------
// fragment q = ni*4+ks, elem: wB[(q*64+lane)*8 + j] = Wc1[k][n], n=ni*16+(lane&15), k=ks*32+(lane>>4)*8+j
__global__ __launch_bounds__(256) void k0_prep(const float* __restrict__ Wc1,
        const float* __restrict__ Wpi, const float* __restrict__ Wsig, const float* __restrict__ Wmu,
        ushort* __restrict__ wB, ushort* __restrict__ wBg) {
    int t = threadIdx.x;
    for (int idx = t; idx < 16384; idx += 256) {
        int j = idx & 7, lane = (idx >> 3) & 63, ks = (idx >> 9) & 3, ni = idx >> 11;
        int lrow = lane & 15, kgrp = lane >> 4;
        int n = ni * 16 + lrow, k = ks * 32 + kgrp * 8 + j;
        wB[idx] = f2bf(Wc1[k * HID + n]);
    }
    for (int idx = t; idx < 4096; idx += 256) {
        int j = idx & 7, lane = (idx >> 3) & 63, ks = (idx >> 9) & 3, ni = (idx >> 11) & 1;
        int lrow = lane & 15, kgrp = lane >> 4;
        int n = ni * 16 + lrow, k = ks * 32 + kgrp * 8 + j;
        float wv = 0.f;
        if (n < 10) wv = Wpi[k * KM + n];
        else if (n < 20) wv = Wsig[k * KM + (n - 10)];
        else if (n < 30) wv = Wmu[k * KM + (n - 20)];
        wBg[idx] = f2bf(wv);
    }
}

// ---------------- k1: U = flig @ W1_top + b1 ; V = frec @ W1_bot ; emit col partials ----------------
__global__ __launch_bounds__(128) void k1_uv(const float* __restrict__ flig,
        const float* __restrict__ frec, const float* __restrict__ W1,
        const float* __restrict__ b1, float* __restrict__ U, float* __restrict__ V,
        float* __restrict__ partS, float* __restrict__ partS2) {
    __shared__ float fr[8][128];
    int bid = blockIdx.x, c = threadIdx.x;
    const float* feat; const float* Wb; float* outp; float bias;
    if (bid < 64) {
        int rowbase = bid * 8;
        feat = flig + rowbase * FD; Wb = W1; outp = U + rowbase * HID; bias = b1[c];
    } else {
        int rowbase = (bid - 64) * 8;
        feat = frec + rowbase * FD; Wb = W1 + FD * HID; outp = V + rowbase * HID; bias = 0.f;
    }
    #pragma unroll
    for (int rr = 0; rr < 8; rr++) fr[rr][c] = feat[rr * FD + c];
    __syncthreads();
    float acc[8];
    #pragma unroll
    for (int rr = 0; rr < 8; rr++) acc[rr] = bias;
    #pragma unroll 4
    for (int k = 0; k < FD; k++) {
        float wv = Wb[k * HID + c];
        #pragma unroll
        for (int rr = 0; rr < 8; rr++) acc[rr] += fr[rr][k] * wv;
    }
    float su = 0.f, su2 = 0.f;
    #pragma unroll
    for (int rr = 0; rr < 8; rr++) {
        outp[rr * HID + c] = acc[rr];
        su += acc[rr]; su2 += acc[rr] * acc[rr];
    }
    partS[bid * 128 + c] = su;
    partS2[bid * 128 + c] = su2;
}

// ---------------- k2a: per-batch reduce of partials ----------------
__global__ __launch_bounds__(256) void k2a(const float* __restrict__ partS, const float* __restrict__ partS2,
        float* __restrict__ SU, float* __restrict__ SU2, float* __restrict__ SV, float* __restrict__ SV2) {
    int b = blockIdx.x, t = threadIdx.x, c = t & 127, half = t >> 7;
    if (half == 0) {
        float s = 0.f, s2 = 0.f;
        #pragma unroll
        for (int j = 0; j < 8; j++) { int row = b * 8 + j; s += partS[row * 128 + c]; s2 += partS2[row * 128 + c]; }
        SU[b * 128 + c] = s; SU2[b * 128 + c] = s2;
    } else {
        float s = 0.f, s2 = 0.f;
        for (int j = 0; j < 64; j++) { int row = 64 + b * 64 + j; s += partS[row * 128 + c]; s2 += partS2[row * 128 + c]; }
        SV[b * 128 + c] = s; SV2[b * 128 + c] = s2;
    }
}

// ---------------- k2b: finalize BN1 scale/shift ----------------
__global__ __launch_bounds__(128) void k2b(const float* __restrict__ SU, const float* __restrict__ SU2,
        const float* __restrict__ SV, const float* __restrict__ SV2,
        const float* __restrict__ g1, const float* __restrict__ beta1,
        float* __restrict__ scale1, float* __restrict__ shift1) {
    int c = threadIdx.x;
    float sum = 0.f, ssq = 0.f;
    #pragma unroll
    for (int b = 0; b < B_; b++) {
        float su = SU[b * 128 + c], sv = SV[b * 128 + c];
        sum += (float)NR * su + (float)NL * sv;
        ssq += (float)NR * SU2[b * 128 + c] + 2.f * su * sv + (float)NL * SV2[b * 128 + c];
    }
    float inv = 1.f / (float)P_;
    float mean = sum * inv;
    float var = ssq * inv - mean * mean;
    float sc = g1[c] * rsqrtf(var + 1e-5f);
    scale1[c] = sc; shift1[c] = beta1[c] - mean * sc;
}

// ---------------- k3: persistent GEMM — z (fragment-order bf16) + BN2 col stats ----------------
// grid 512: block bid owns lig row bl=bid, processes 4 tiles of 128 pairs (rec quarters).
__global__ __launch_bounds__(256, 2) void k3_gemm(const float* __restrict__ U, const float* __restrict__ V,
        const ushort* __restrict__ wB, const float* __restrict__ bc1,
        const float* __restrict__ scale1, const float* __restrict__ shift1,
        ushort* __restrict__ z, float* __restrict__ bn2s, float* __restrict__ bn2s2) {
    __shared__ ushort hT[128 * LDH];     // 34816 B
    __shared__ ushort wLds[16384];       // 32768 B
    __shared__ float sred[4][128];       // 2048 B
    __shared__ float s2red[4][128];      // 2048 B  -> 71.7 KB total => 2 blocks/CU
    int bid = blockIdx.x, t = threadIdx.x;
    int w = t >> 6, lane = t & 63, lrow = lane & 15, kgrp = lane >> 4, wrow = w * 32;
    // stage Wc1 B-fragments into LDS once
    for (int i = t; i < 2048; i += 256)
        *(bf16x8*)&wLds[i * 8] = *(const bf16x8*)&wB[i * 8];
    float bc1v[8], s[8], s2[8];
    #pragma unroll
    for (int ni = 0; ni < 8; ni++) { bc1v[ni] = bc1[ni * 16 + lrow]; s[ni] = 0.f; s2[ni] = 0.f; }
    int bl = bid;
    int c8 = (t & 15) * 8, rg = t >> 4;
    float4 u0 = *(const float4*)&U[bl * HID + c8];
    float4 u1 = *(const float4*)&U[bl * HID + c8 + 4];
    float4 sc0 = *(const float4*)&scale1[c8], sc1 = *(const float4*)&scale1[c8 + 4];
    float4 sh0 = *(const float4*)&shift1[c8], sh1 = *(const float4*)&shift1[c8 + 4];
    for (int it = 0; it < 4; it++) {
        int tile = bid * 4 + it;
        int vbase = bl * 512 - ((bl >> 6) << 9) + ((bl >> 6) << 9) + it * 128; // = (bl's batch)*512 + it*128
        vbase = ((bl >> 6) << 9) + it * 128;
        __syncthreads();   // hT safe to overwrite (also covers wLds at it=0)
        // stage h tile: h = elu((U+V)*scale1 + shift1)
        #pragma unroll
        for (int rr = rg; rr < 128; rr += 16) {
            const float* vp = &V[(vbase + rr) * HID + c8];
            float4 v0 = *(const float4*)vp, v1 = *(const float4*)(vp + 4);
            union { bf16x8 v; ushort u[8]; } o;
            o.u[0] = f2bf(elu1(fmaf(u0.x + v0.x, sc0.x, sh0.x)));
            o.u[1] = f2bf(elu1(fmaf(u0.y + v0.y, sc0.y, sh0.y)));
            o.u[2] = f2bf(elu1(fmaf(u0.z + v0.z, sc0.z, sh0.z)));
            o.u[3] = f2bf(elu1(fmaf(u0.w + v0.w, sc0.w, sh0.w)));
            o.u[4] = f2bf(elu1(fmaf(u1.x + v1.x, sc1.x, sh1.x)));
            o.u[5] = f2bf(elu1(fmaf(u1.y + v1.y, sc1.y, sh1.y)));
            o.u[6] = f2bf(elu1(fmaf(u1.z + v1.z, sc1.z, sh1.z)));
            o.u[7] = f2bf(elu1(fmaf(u1.w + v1.w, sc1.w, sh1.w)));
            *(bf16x8*)&hT[rr * LDH + c8] = o.v;
        }
        __syncthreads();
        f32x4 acc[2][8];
        #pragma unroll
        for (int mi = 0; mi < 2; mi++)
            #pragma unroll
            for (int ni = 0; ni < 8; ni++) acc[mi][ni] = (f32x4){0.f, 0.f, 0.f, 0.f};
        #pragma unroll
        for (int ks = 0; ks < 4; ks++) {
            int ko = ks * 32 + kgrp * 8;
            bf16x8 a0 = *(const bf16x8*)&hT[(wrow + lrow) * LDH + ko];
            bf16x8 a1 = *(const bf16x8*)&hT[(wrow + 16 + lrow) * LDH + ko];
            #pragma unroll
            for (int ni = 0; ni < 8; ni++) {
                bf16x8 bfr = *(const bf16x8*)&wLds[((ni * 4 + ks) * 64 + lane) * 8];
                acc[0][ni] = __builtin_amdgcn_mfma_f32_16x16x32_bf16(a0, bfr, acc[0][ni], 0, 0, 0);
                acc[1][ni] = __builtin_amdgcn_mfma_f32_16x16x32_bf16(a1, bfr, acc[1][ni], 0, 0, 0);
            }
        }
        // epilogue: bias + stats + fragment-order z store (1KB contiguous per wave instr)
        #pragma unroll
        for (int mi = 0; mi < 2; mi++)
            #pragma unroll
            for (int reg = 0; reg < 4; reg++) {
                union { bf16x8 v; ushort u[8]; } o;
                #pragma unroll
                for (int ni = 0; ni < 8; ni++) {
                    float vv = acc[mi][ni][reg] + bc1v[ni];
                    s[ni] += vv; s2[ni] += vv * vv;
                    o.u[ni] = f2bf(vv);
                }
                int vrow = mi * 4 + reg;
                *(bf16x8*)&z[(((tile * 4 + w) * 8 + vrow) * 64 + lane) * 8] = o.v;
            }
    }
    #pragma unroll
    for (int ni = 0; ni < 8; ni++) {
        s[ni] += __shfl_xor(s[ni], 16);  s[ni] += __shfl_xor(s[ni], 32);
        s2[ni] += __shfl_xor(s2[ni], 16); s2[ni] += __shfl_xor(s2[ni], 32);
    }
    if (lane < 16) {
        #pragma unroll
        for (int ni = 0; ni < 8; ni++) { sred[w][ni * 16 + lane] = s[ni]; s2red[w][ni * 16 + lane] = s2[ni]; }
    }
    __syncthreads();
    if (t < 128) {
        bn2s[bid * 128 + t]  = sred[0][t] + sred[1][t] + sred[2][t] + sred[3][t];
        bn2s2[bid * 128 + t] = s2red[0][t] + s2red[1][t] + s2red[2][t] + s2red[3][t];
    }
}

// ---------------- k4a/k4b: reduce BN2 partials (512 rows) -> epilogue params ----------------
__global__ __launch_bounds__(256) void k4a(const float* __restrict__ bn2s, const float* __restrict__ bn2s2,
        float* __restrict__ l2s, float* __restrict__ l2s2) {
    int j = blockIdx.x, t = threadIdx.x, c = t & 127, half = t >> 7;
    float s = 0, s2 = 0;
    #pragma unroll
    for (int rr = half; rr < 8; rr += 2) {
        int row = j * 8 + rr;
        s += bn2s[row * 128 + c]; s2 += bn2s2[row * 128 + c];
    }
    __shared__ float red[2][2][128];
    red[0][half][c] = s; red[1][half][c] = s2;
    __syncthreads();
    if (t < 128) { l2s[j * 128 + t] = red[0][0][t] + red[0][1][t]; l2s2[j * 128 + t] = red[1][0][t] + red[1][1][t]; }
}

__global__ __launch_bounds__(128) void k4b(const float* __restrict__ l2s, const float* __restrict__ l2s2,
        const float* __restrict__ gc, const float* __restrict__ betac,
        float* __restrict__ Af, float* __restrict__ Bf) {
    int c = threadIdx.x;
    float s = 0, s2 = 0;
    #pragma unroll
    for (int j = 0; j < 64; j++) { s += l2s[j * 128 + c]; s2 += l2s2[j * 128 + c]; }
    float inv = 1.f / (float)P_;
    float mean = s * inv, var = s2 * inv - mean * mean;
    float sc = gc[c] * rsqrtf(var + 1e-5f);
    Af[c] = sc;
    Bf[c] = betac[c] - mean * sc;   // z already contains bc1
}

// ---------------- k5: streaming contact epilogue over fragment-order z ----------------
__global__ __launch_bounds__(256) void k5_contact(const ushort* __restrict__ z,
        const float* __restrict__ Af, const float* __restrict__ Bf,
        const float* __restrict__ Wc2, const float* __restrict__ bc2,
        const float* __restrict__ posl, const float* __restrict__ posr,
        float* __restrict__ outc, float* __restrict__ outt) {
    int bid = blockIdx.x, t = threadIdx.x;
    int w = t >> 6, lane = t & 63, lrow = lane & 15, kgrp = lane >> 4;
    float av[8], bv[8], wv[8];
    #pragma unroll
    for (int ni = 0; ni < 8; ni++) {
        int c = ni * 16 + lrow;
        av[ni] = Af[c]; bv[ni] = Bf[c]; wv[ni] = Wc2[c];
    }
    float bc2v = bc2[0];
    int i0 = bid * 128;
    #pragma unroll
    for (int vrow = 0; vrow < 8; vrow++) {
        bf16x8 zv = *(const bf16x8*)&z[(((bid * 4 + w) * 8 + vrow) * 64 + lane) * 8];
        float s = 0.f;
        #pragma unroll
        for (int ni = 0; ni < 8; ni++) {
            float x = fmaf(bf2f((ushort)zv[ni]), av[ni], bv[ni]);
            s += fmaxf(x, 0.f) * wv[ni];
        }
        s += __shfl_xor(s, 1); s += __shfl_xor(s, 2); s += __shfl_xor(s, 4); s += __shfl_xor(s, 8);
        if (lrow == 0) {
            int rloc = w * 32 + (vrow >> 2) * 16 + kgrp * 4 + (vrow & 3);
            int row = i0 + rloc;
            outc[row] = s + bc2v;
            int bl = row >> 9, b = row >> 15, r = row & 511;
            float dx = posl[bl * 3]     - posr[(b * NR + r) * 3];
            float dy = posl[bl * 3 + 1] - posr[(b * NR + r) * 3 + 1];
            float dz = posl[bl * 3 + 2] - posr[(b * NR + r) * 3 + 2];
            float y = sqrtf(dx * dx + dy * dy + dz * dz);
            outt[row] = (y < 8.0f) ? 1.0f : 0.0f;
        }
    }
}

// ---------------- k6: MDN (gather h via U+V recompute, 128x32 MFMA, coalesced outputs) ----------------
__global__ __launch_bounds__(256) void k6_mdn(const int* __restrict__ mask,
        const float* __restrict__ U, const float* __restrict__ V,
        const float* __restrict__ scale1, const float* __restrict__ shift1,
        const ushort* __restrict__ wBg,
        const float* __restrict__ bpi, const float* __restrict__ bsig, const float* __restrict__ bmu,
        const float* __restrict__ posl, const float* __restrict__ posr,
        float* __restrict__ out_logpi, float* __restrict__ out_sigma, float* __restrict__ out_mu,
        float* __restrict__ mdn_psum, float* __restrict__ mdn_pcnt) {
    __shared__ ushort hT[128 * LDH];
    float* stageF = (float*)hT;                 // aliased scratch (barriers guard reuse)
    float* zl   = stageF;                        // 128*33 = 4224 floats
    float* bufA = stageF + 4352;                 // 1280 floats (16B aligned)
    float* bufB = stageF + 4352 + 1280;
    float* bufC = stageF + 4352 + 2560;          // ends at 8192 floats = 32768B < 34816B
    __shared__ int midx[128];
    __shared__ float mdnv[128];
    __shared__ int mdnb[128];
    int bid = blockIdx.x, t = threadIdx.x;
    int m0 = bid * 128;
    if (t < 128) midx[t] = mask[m0 + t];
    __syncthreads();
    {
        int c8 = (t & 15) * 8, rg = t >> 4;
        float4 sc0 = *(const float4*)&scale1[c8], sc1 = *(const float4*)&scale1[c8 + 4];
        float4 sh0 = *(const float4*)&shift1[c8], sh1 = *(const float4*)&shift1[c8 + 4];
        #pragma unroll
        for (int rr = rg; rr < 128; rr += 16) {
            int i = midx[rr];
            int bl = i >> 9, b = i >> 15, r = i & 511;
            const float* up = &U[bl * HID + c8];
            const float* vp = &V[(b * NR + r) * HID + c8];
            float4 u0 = *(const float4*)up, u1 = *(const float4*)(up + 4);
            float4 v0 = *(const float4*)vp, v1 = *(const float4*)(vp + 4);
            union { bf16x8 v; ushort u[8]; } o;
            o.u[0] = f2bf(elu1(fmaf(u0.x + v0.x, sc0.x, sh0.x)));
            o.u[1] = f2bf(elu1(fmaf(u0.y + v0.y, sc0.y, sh0.y)));
            o.u[2] = f2bf(elu1(fmaf(u0.z + v0.z, sc0.z, sh0.z)));
            o.u[3] = f2bf(elu1(fmaf(u0.w + v0.w, sc0.w, sh0.w)));
            o.u[4] = f2bf(elu1(fmaf(u1.x + v1.x, sc1.x, sh1.x)));
            o.u[5] = f2bf(elu1(fmaf(u1.y + v1.y, sc1.y, sh1.y)));
            o.u[6] = f2bf(elu1(fmaf(u1.z + v1.z, sc1.z, sh1.z)));
            o.u[7] = f2bf(elu1(fmaf(u1.w + v1.w, sc1.w, sh1.w)));
            *(bf16x8*)&hT[rr * LDH + c8] = o.v;
        }
    }
    __syncthreads();
    int w = t >> 6, lane = t & 63;
    int wrow = w * 32, lrow = lane & 15, kgrp = lane >> 4;
    f32x4 acc[2][2];
    #pragma unroll
    for (int mi = 0; mi < 2; mi++)
        #pragma unroll
        for (int ni = 0; ni < 2; ni++) acc[mi][ni] = (f32x4){0.f, 0.f, 0.f, 0.f};
    const bf16x8* wBv = (const bf16x8*)wBg;
    #pragma unroll
    for (int ks = 0; ks < 4; ks++) {
        int ko = ks * 32 + kgrp * 8;
        bf16x8 a0 = *(const bf16x8*)&hT[(wrow + lrow) * LDH + ko];
        bf16x8 a1 = *(const bf16x8*)&hT[(wrow + 16 + lrow) * LDH + ko];
        bf16x8 b0 = wBv[ks * 64 + lane];
        bf16x8 b1 = wBv[(4 + ks) * 64 + lane];
        acc[0][0] = __builtin_amdgcn_mfma_f32_16x16x32_bf16(a0, b0, acc[0][0], 0, 0, 0);
        acc[0][1] = __builtin_amdgcn_mfma_f32_16x16x32_bf16(a0, b1, acc[0][1], 0, 0, 0);
        acc[1][0] = __builtin_amdgcn_mfma_f32_16x16x32_bf16(a1, b0, acc[1][0], 0, 0, 0);
        acc[1][1] = __builtin_amdgcn_mfma_f32_16x16x32_bf16(a1, b1, acc[1][1], 0, 0, 0);
    }
    __syncthreads();   // all hT reads done before zl alias writes
    #pragma unroll
    for (int mi = 0; mi < 2; mi++)
        #pragma unroll
        for (int ni = 0; ni < 2; ni++)
            #pragma unroll
            for (int reg = 0; reg < 4; reg++) {
                int row = wrow + mi * 16 + kgrp * 4 + reg;
                zl[row * 33 + ni * 16 + lrow] = acc[mi][ni][reg];
            }
    __syncthreads();
    if (t < 128) {
        float zv[30];
        #pragma unroll
        for (int j = 0; j < 30; j++) zv[j] = zl[t * 33 + j];
        float lp[10], mx = -1e30f;
        #pragma unroll
        for (int j = 0; j < 10; j++) { lp[j] = zv[j] + bpi[j]; mx = fmaxf(mx, lp[j]); }
        float se = 0.f;
        #pragma unroll
        for (int j = 0; j < 10; j++) se += __expf(lp[j] - mx);
        float lse = mx + __logf(se);
        #pragma unroll
        for (int j = 0; j < 10; j++) lp[j] -= lse;
        float sg[10], muv[10];
        #pragma unroll
        for (int j = 0; j < 10; j++) sg[j] = elu1(zv[10 + j] + bsig[j]) + 1.1f;
        #pragma unroll
        for (int j = 0; j < 10; j++) muv[j] = elu1(zv[20 + j] + bmu[j]) + 1.0f;
        int i = midx[t];
        int bl = i >> 9, b = i >> 15, r = i & 511;
        float dx = posl[bl * 3]     - posr[(b * NR + r) * 3];
        float dy = posl[bl * 3 + 1] - posr[(b * NR + r) * 3 + 1];
        float dz = posl[bl * 3 + 2] - posr[(b * NR + r) * 3 + 2];
        float y = sqrtf(dx * dx + dy * dy + dz * dz);
        float tt[10], mm = -1e30f;
        #pragma unroll
        for (int j = 0; j < 10; j++) {
            float q = (y - muv[j]) / sg[j];
            float llv = -0.5f * q * q - __logf(sg[j]) - 0.91893853320467274f;
            tt[j] = lp[j] + llv; mm = fmaxf(mm, tt[j]);
        }
        float s2e = 0.f;
        #pragma unroll
        for (int j = 0; j < 10; j++) s2e += __expf(tt[j] - mm);
        float mdn = -(mm + __logf(s2e));
        #pragma unroll
        for (int j = 0; j < 10; j++) { bufA[t * 10 + j] = lp[j]; bufB[t * 10 + j] = sg[j]; bufC[t * 10 + j] = muv[j]; }
        mdnv[t] = mdn; mdnb[t] = b;
    }
    __syncthreads();
    // coalesced float4 copy-out: 320 float4 per array
    {
        float4* oA = (float4*)&out_logpi[m0 * 10];
        float4* oB = (float4*)&out_sigma[m0 * 10];
        float4* oC = (float4*)&out_mu[m0 * 10];
        const float4* bA = (const float4*)bufA;
        const float4* bB = (const float4*)bufB;
        const float4* bC = (const float4*)bufC;
        #pragma unroll
        for (int i4 = t; i4 < 320; i4 += 256) { oA[i4] = bA[i4]; oB[i4] = bB[i4]; oC[i4] = bC[i4]; }
    }
    if (t < 8) {  // deterministic fixed-order per-batch partial sums
        float s = 0.f; int cnt = 0;
        for (int rr = 0; rr < 128; rr++) if (mdnb[rr] == t) { s += mdnv[rr]; cnt++; }
        mdn_psum[bid * 8 + t] = s; mdn_pcnt[bid * 8 + t] = (float)cnt;
    }
}

// ---------------- k7: prob = segment mean ----------------
__global__ __launch_bounds__(256) void k7_prob(const float* __restrict__ psum, const float* __restrict__ pcnt,
        float* __restrict__ prob) {
    int b = blockIdx.x, t = threadIdx.x;
    float s = 0, c = 0;
    for (int idx = t; idx < 1024; idx += 256) { s += psum[idx * 8 + b]; c += pcnt[idx * 8 + b]; }
    __shared__ float rs[256], rc[256];
    rs[t] = s; rc[t] = c;
    __syncthreads();
    for (int off = 128; off > 0; off >>= 1) {
        if (t < off) { rs[t] += rs[t + off]; rc[t] += rc[t + off]; }
        __syncthreads();
    }
    if (t == 0) prob[b] = rs[0] / fmaxf(rc[0], 1.f);
}

extern "C" void kernel_launch(void* const* d_in, const int* in_sizes, int n_in,
                              void* d_out, int out_size, void* d_ws, size_t ws_size,
                              hipStream_t stream) {
    const float* flig  = (const float*)d_in[0];
    const float* posl  = (const float*)d_in[1];
    const float* frec  = (const float*)d_in[3];
    const float* posr  = (const float*)d_in[4];
    const int*   mask  = (const int*)d_in[6];
    const float* W1    = (const float*)d_in[7];
    const float* b1    = (const float*)d_in[8];
    const float* g1    = (const float*)d_in[9];
    const float* beta1 = (const float*)d_in[10];
    const float* Wpi   = (const float*)d_in[11];
    const float* bpi   = (const float*)d_in[12];
    const float* Wsig  = (const float*)d_in[13];
    const float* bsig  = (const float*)d_in[14];
    const float* Wmu   = (const float*)d_in[15];
    const float* bmu   = (const float*)d_in[16];
    const float* Wc1   = (const float*)d_in[17];
    const float* bc1   = (const float*)d_in[18];
    const float* gc    = (const float*)d_in[19];
    const float* betac = (const float*)d_in[20];
    const float* Wc2   = (const float*)d_in[21];
    const float* bc2   = (const float*)d_in[22];

    float* ws = (float*)d_ws;
    float* U      = ws;                 // 65536
    float* V      = ws + 65536;         // 524288 (end 589824)
    float* scale1 = ws + 589824;        // 128
    float* shift1 = ws + 589952;
    float* Af     = ws + 590080;
    float* Bf     = ws + 590208;        // (end 590336)
    float* SU     = ws + 590336;        // 1024
    float* SU2    = ws + 591360;
    float* SV     = ws + 592384;
    float* SV2    = ws + 593408;        // (end 594432)
    ushort* wB    = (ushort*)(ws + 594432);   // 16384 bf16 (end 602624)
    ushort* wBg   = (ushort*)(ws + 602624);   // 4096 bf16 (end 604672)
    float* bn2s   = ws + 604672;        // 512*128 (end 670208)
    float* bn2s2  = ws + 670208;        // (end 735744)
    float* psum   = ws + 735744;        // 8192 (end 743936)
    float* pcnt   = ws + 743936;        // (end 752128)
    ushort* zbuf  = (ushort*)(ws + 752128);   // P*128 bf16 = 67.1 MB (fragment order)
    // partS/partS2 alias zbuf region: dead before k3 writes z (stream-ordered)
    float* partS  = ws + 752128;        // 576*128
    float* partS2 = ws + 825856;        // (end 899584)
    // l2s/l2s2 share psum/pcnt: lifetimes [k4a..k4b] vs [k6..k7] are disjoint
    float* l2s1_  = psum;
    float* l2s2_  = pcnt;

    float* out = (float*)d_out;
    float* out_logpi   = out;
    float* out_sigma   = out + 1310720;
    float* out_mu      = out + 2621440;
    float* out_prob    = out + 3932160;
    float* out_contact = out + 3932168;
    float* out_truth   = out + 4194312;

    k0_prep<<<dim3(1), dim3(256), 0, stream>>>(Wc1, Wpi, Wsig, Wmu, wB, wBg);
    k1_uv<<<dim3(576), dim3(128), 0, stream>>>(flig, frec, W1, b1, U, V, partS, partS2);
    k2a<<<dim3(8), dim3(256), 0, stream>>>(partS, partS2, SU, SU2, SV, SV2);
    k2b<<<dim3(1), dim3(128), 0, stream>>>(SU, SU2, SV, SV2, g1, beta1, scale1, shift1);
    k3_gemm<<<dim3(512), dim3(256), 0, stream>>>(U, V, wB, bc1, scale1, shift1, zbuf, bn2s, bn2s2);
    k4a<<<dim3(64), dim3(256), 0, stream>>>(bn2s, bn2s2, l2s1_, l2s2_);
    k4b<<<dim3(1), dim3(128), 0, stream>>>(l2s1_, l2s2_, gc, betac, Af, Bf);
    k5_contact<<<dim3(2048), dim3(256), 0, stream>>>(zbuf, Af, Bf, Wc2, bc2, posl, posr, out_contact, out_truth);
    k6_mdn<<<dim3(1024), dim3(256), 0, stream>>>(mask, U, V, scale1, shift1, wBg,
        bpi, bsig, bmu, posl, posr, out_logpi, out_sigma, out_mu, psum, pcnt);
    k7_prob<<<dim3(8), dim3(256), 0, stream>>>(psum, pcnt, out_prob);
}